// Round 4
// baseline (303.749 us; speedup 1.0000x reference)
//
#include <hip/hip_runtime.h>
#include <hip/hip_bf16.h>
#include <math.h>

#define B_ 8
#define S_ 192
#define D_ 512
#define L_ 8
#define SQ 1536   // S_*L_
#define H_ 2048
#define NROW (B_*SQ)   // 12288
#define SCALE_QK 0.04419417382415922f  // 1/sqrt(512)

typedef unsigned short ushort_t;
typedef unsigned int uint_t;
typedef __attribute__((ext_vector_type(8))) short bf16x8;
typedef __attribute__((ext_vector_type(4))) float f32x4;
typedef __attribute__((ext_vector_type(16))) float f32x16;

__device__ __forceinline__ float bfu2f(ushort_t u) { return __uint_as_float((unsigned)u << 16); }
__device__ __forceinline__ ushort_t f2bfu(float f) {
  __hip_bfloat16 h = __float2bfloat16(f);
  return *reinterpret_cast<ushort_t*>(&h);
}

// tanh-form GELU: 0.5x(1+tanh(0.79788456(x+0.044715x^3))), max |err| ~3e-4.
__device__ __forceinline__ float gelu_tanh(float x) {
  float x2 = x * x;
  float u2 = x * fmaf(0.0713548162f, x2, 1.5957691216f);
  float e = __expf(u2);                       // e^(2u)
  float r = fmaf(-2.0f, __builtin_amdgcn_rcpf(e + 1.0f), 1.0f);  // tanh(u)
  float hx = 0.5f * x;
  return fmaf(hx, r, hx);
}

// async global->LDS, 16B per lane; LDS dest = wave-uniform base + lane*16
__device__ __forceinline__ void gl_lds16(const ushort_t* g, ushort_t* l) {
  __builtin_amdgcn_global_load_lds(
      (const __attribute__((address_space(1))) unsigned int*)g,
      (__attribute__((address_space(3))) unsigned int*)l, 16, 0, 0);
}

// counted vmcnt wait: leaves N newest VMEM ops in flight (T4).
#define VMWAIT(N) asm volatile("s_waitcnt vmcnt(" #N ")" ::: "memory")

// ---- fast build x: one block per (b,si); coalesced read of 4096 floats, LDS transpose.
// Emits x (f32), x_bf (bf16) and xT_bf ([B][D][SQ]) directly.
__global__ __launch_bounds__(256) void k_build_x_f(const float* __restrict__ lags,
                                                   float* __restrict__ x,
                                                   ushort_t* __restrict__ x_bf,
                                                   ushort_t* __restrict__ xT) {
  __shared__ float tile[512][9];
  const int tid = threadIdx.x;
  const float* in = lags + (size_t)blockIdx.x * 4096;
  #pragma unroll
  for (int it = 0; it < 4; ++it) {
    int f = (tid + it * 256) * 4;
    float4 v = *reinterpret_cast<const float4*>(in + f);
    int k = f >> 3, l0 = f & 7;
    tile[k][l0] = v.x; tile[k][l0 + 1] = v.y; tile[k][l0 + 2] = v.z; tile[k][l0 + 3] = v.w;
  }
  __syncthreads();
  const int l = tid >> 5, kbase = tid & 31;
  const size_t r = (size_t)blockIdx.x * 8 + l;
  #pragma unroll
  for (int j = 0; j < 16; ++j) {
    int k = kbase + 32 * j;
    float v = tile[k][l];
    x[r * D_ + k] = v;
    x_bf[r * D_ + k] = f2bfu(v);
  }
  const int b = blockIdx.x / S_, si = blockIdx.x - b * S_;
  #pragma unroll
  for (int dd = 0; dd < 2; ++dd) {
    int d = tid + dd * 256;
    uint_t pk[4];
    #pragma unroll
    for (int j = 0; j < 4; ++j) {
      uint_t lo = f2bfu(tile[d][2 * j]);
      uint_t hi = f2bfu(tile[d][2 * j + 1]);
      pk[j] = (hi << 16) | lo;
    }
    uint_t* dst = (uint_t*)(xT + ((size_t)b * D_ + d) * SQ + si * 8);
    *reinterpret_cast<uint4*>(dst) = make_uint4(pk[0], pk[1], pk[2], pk[3]);
  }
}

// ---- cast + transpose weights: W[K][N] fp32 -> Wt[N][K] bf16 ----
__global__ __launch_bounds__(256) void k_wt(const float* __restrict__ W,
                                            ushort_t* __restrict__ Wt,
                                            int K, int N) {
  __shared__ ushort_t tile[64][65];
  int n0 = blockIdx.x * 64, k0 = blockIdx.y * 64;
  for (int i = threadIdx.x; i < 4096; i += 256) {
    int kk = i >> 6, nn = i & 63;
    tile[nn][kk] = f2bfu(W[(size_t)(k0 + kk) * N + n0 + nn]);
  }
  __syncthreads();
  for (int i = threadIdx.x; i < 4096; i += 256) {
    int nn = i >> 6, kk = i & 63;
    Wt[(size_t)(n0 + nn) * K + k0 + kk] = tile[nn][kk];
  }
}

// ---- bf16 MFMA GEMM, 32x32x16 MFMA, BK=64, double-buffered async staging,
//      counted vmcnt pipeline:  C[M,N] = A[M,K] @ Bt[N,K]^T
// MODE 0: +bias, gelu -> bf16 | 1: +bias -> f32 | 2: *scale -> bf16 | 3: -> f32
//
// PAIR-INTERLEAVED LDS layout (conflict fix, r4): for a 128-row x 64-ushort
// tile, element (row R, oct c) [oct = 8-ushort chunk, c in 0..7] lives at
//   byte(R,c) = (R>>1)*256 + ((c ^ ((R>>1)&7)))*32 + (R&1)*16
// -> rows 2m,2m+1 share one 32B unit per oct, so the MFMA read (lane pairs
// 2m,2m+1 need rows 2m,2m+1 at the same oct) hits adjacent 16B halves of one
// aligned 32B unit (mergeable), and the XOR spreads units over all 4
// bank-groups evenly. Staging keeps linear global_load_lds (dest lane*16B) by
// pre-permuting the per-lane GLOBAL source:
//   lane l, step j: row = j*8 + 2*(l>>4) + (l&1),
//                   oct = ((l>>1)&7) ^ (l>>4) ^ (4*(j&1))
template<int MODE>
__global__ __launch_bounds__(256) void k_gemm(const ushort_t* __restrict__ A,
                                              const ushort_t* __restrict__ Bt,
                                              const float* __restrict__ bias,
                                              void* __restrict__ Cout,
                                              int M, int K, int N,
                                              size_t sAz, size_t sBz, size_t sCz,
                                              float scale) {
  A  += (size_t)blockIdx.z * sAz;
  Bt += (size_t)blockIdx.z * sBz;
  __shared__ ushort_t As0[128 * 64];   // 16 KB each, 64 KB total
  __shared__ ushort_t As1[128 * 64];
  __shared__ ushort_t Bs0[128 * 64];
  __shared__ ushort_t Bs1[128 * 64];
  const int tid = threadIdx.x;
  const int m0 = blockIdx.y * 128, n0 = blockIdx.x * 128;
  const int w = tid >> 6, lane = tid & 63;
  const int wr = w >> 1, wc = w & 1;
  const int l31 = lane & 31, khi = lane >> 5;
  // staging source (pair-interleaved; see header comment)
  const int rowlane = 2 * (lane >> 4) + (lane & 1);   // 0..7
  const int c0 = ((lane >> 1) & 7) ^ (lane >> 4);     // oct for even j
  const int dC = 32 - ((c0 & 4) << 4);                // ((c0^4)-c0)*8 ushorts
  // fragment-read addressing
  const int p7 = (lane >> 1) & 7;
  const int rb = (l31 >> 1) * 128 + (lane & 1) * 8;   // per-lane read base (ushorts)
  const int lbase = w * 2048;                         // wave staging region (ushorts)
  const size_t sK8 = (size_t)8 * K;

  f32x16 acc[2][2];
  if (MODE <= 1) {
    #pragma unroll
    for (int nj = 0; nj < 2; ++nj) {
      float bv = bias[n0 + wc * 64 + nj * 32 + l31];
      #pragma unroll
      for (int mi = 0; mi < 2; ++mi)
        #pragma unroll
        for (int rg = 0; rg < 16; ++rg) acc[mi][nj][rg] = bv;
    }
  } else {
    #pragma unroll
    for (int nj = 0; nj < 2; ++nj)
      #pragma unroll
      for (int mi = 0; mi < 2; ++mi)
        #pragma unroll
        for (int rg = 0; rg < 16; ++rg) acc[mi][nj][rg] = 0.f;
  }

  const ushort_t* gA = A  + (size_t)(m0 + w * 32 + rowlane) * K + c0 * 8;
  const ushort_t* gB = Bt + (size_t)(n0 + w * 32 + rowlane) * K + c0 * 8;

#define STAGE(AS, BS) do {                                                  \
    ushort_t* la_ = &AS[lbase]; ushort_t* lb_ = &BS[lbase];                 \
    gl_lds16(gA,                     la_);                                  \
    gl_lds16(gB,                     lb_);                                  \
    gl_lds16(gA + sK8 + dC,          la_ + 512);                            \
    gl_lds16(gB + sK8 + dC,          lb_ + 512);                            \
    gl_lds16(gA + 2 * sK8,           la_ + 1024);                           \
    gl_lds16(gB + 2 * sK8,           lb_ + 1024);                           \
    gl_lds16(gA + 3 * sK8 + dC,      la_ + 1536);                           \
    gl_lds16(gB + 3 * sK8 + dC,      lb_ + 1536);                           \
    gA += 64; gB += 64;                                                     \
  } while (0)

#define COMPUTE(AS, BS) do {                                                \
    _Pragma("unroll")                                                       \
    for (int ks_ = 0; ks_ < 4; ++ks_) {                                     \
      const int px_ = ((ks_ * 2 + khi) ^ p7) * 16;                          \
      bf16x8 af_[2], bf_[2];                                                \
      _Pragma("unroll")                                                     \
      for (int mi_ = 0; mi_ < 2; ++mi_)                                     \
        af_[mi_] = *reinterpret_cast<const bf16x8*>(                        \
            &AS[wr * 4096 + mi_ * 2048 + rb + px_]);                        \
      _Pragma("unroll")                                                     \
      for (int nj_ = 0; nj_ < 2; ++nj_)                                     \
        bf_[nj_] = *reinterpret_cast<const bf16x8*>(                        \
            &BS[wc * 4096 + nj_ * 2048 + rb + px_]);                        \
      _Pragma("unroll")                                                     \
      for (int mi_ = 0; mi_ < 2; ++mi_)                                     \
        _Pragma("unroll")                                                   \
        for (int nj_ = 0; nj_ < 2; ++nj_)                                   \
          acc[mi_][nj_] = __builtin_amdgcn_mfma_f32_32x32x16_bf16(          \
              af_[mi_], bf_[nj_], acc[mi_][nj_], 0, 0, 0);                  \
    }                                                                       \
  } while (0)

  // prologue: stage tiles 0 and 1 (16 loads/wave in flight)
  STAGE(As0, Bs0);
  STAGE(As1, Bs1);

  const int nt = K >> 6;   // even, >= 8 for all call sites
  for (int t = 0; t < nt - 2; t += 2) {
    VMWAIT(8);                        // tile t landed; tile t+1 stays in flight
    __builtin_amdgcn_s_barrier();
    COMPUTE(As0, Bs0);                // compute tile t
    __builtin_amdgcn_s_barrier();     // join: all waves done reading buf0
    STAGE(As0, Bs0);                  // prefetch tile t+2
    VMWAIT(8);                        // tile t+1 landed; tile t+2 in flight
    __builtin_amdgcn_s_barrier();
    COMPUTE(As1, Bs1);                // compute tile t+1
    __builtin_amdgcn_s_barrier();     // join: all waves done reading buf1
    STAGE(As1, Bs1);                  // prefetch tile t+3
  }
  // tail: tiles nt-2 (buf0) and nt-1 (buf1) staged, nothing more to prefetch
  VMWAIT(8);
  __builtin_amdgcn_s_barrier();
  COMPUTE(As0, Bs0);
  VMWAIT(0);
  __builtin_amdgcn_s_barrier();
  COMPUTE(As1, Bs1);

#undef STAGE
#undef COMPUTE

  ushort_t* Cb = (ushort_t*)Cout + (size_t)blockIdx.z * sCz;
  float*    Cf = (float*)Cout    + (size_t)blockIdx.z * sCz;
  #pragma unroll
  for (int mi = 0; mi < 2; ++mi)
    #pragma unroll
    for (int nj = 0; nj < 2; ++nj) {
      int gc = n0 + wc * 64 + nj * 32 + l31;
      #pragma unroll
      for (int rg = 0; rg < 16; ++rg) {
        int gr = m0 + wr * 64 + mi * 32 + (rg & 3) + 8 * (rg >> 2) + 4 * khi;
        float v = acc[mi][nj][rg];
        if (MODE == 0) {
          Cb[(size_t)gr * N + gc] = f2bfu(gelu_tanh(v));
        } else if (MODE == 1) {
          Cf[(size_t)gr * N + gc] = v;
        } else if (MODE == 2) {
          Cb[(size_t)gr * N + gc] = f2bfu(v * scale);
        } else {
          Cf[(size_t)gr * N + gc] = v;
        }
      }
    }
}

// ---- softmax rows in place, bf16 storage (uint-packed), fp32 math ----
__global__ __launch_bounds__(256) void k_softmax_bf(ushort_t* __restrict__ sc) {
  uint_t* row = (uint_t*)(sc + (size_t)blockIdx.z * SQ * SQ + (size_t)blockIdx.x * SQ);
  int tid = threadIdx.x;
  __shared__ float red[8];
  float v[6];
  float m = -1e30f;
  #pragma unroll
  for (int k = 0; k < 3; ++k) {
    uint_t u = row[tid + k * 256];
    v[2*k]   = __uint_as_float(u << 16);
    v[2*k+1] = __uint_as_float(u & 0xffff0000u);
    m = fmaxf(m, fmaxf(v[2*k], v[2*k+1]));
  }
  #pragma unroll
  for (int o = 32; o > 0; o >>= 1) m = fmaxf(m, __shfl_down(m, o));
  if ((tid & 63) == 0) red[tid >> 6] = m;
  __syncthreads();
  m = fmaxf(fmaxf(red[0], red[1]), fmaxf(red[2], red[3]));
  __syncthreads();
  float ssum = 0.f;
  #pragma unroll
  for (int k = 0; k < 6; ++k) { v[k] = expf(v[k] - m); ssum += v[k]; }
  #pragma unroll
  for (int o = 32; o > 0; o >>= 1) ssum += __shfl_down(ssum, o);
  if ((tid & 63) == 0) red[4 + (tid >> 6)] = ssum;
  __syncthreads();
  float inv = 1.0f / (red[4] + red[5] + red[6] + red[7]);
  #pragma unroll
  for (int k = 0; k < 3; ++k) {
    uint_t lo = f2bfu(v[2*k] * inv);
    uint_t hi = f2bfu(v[2*k+1] * inv);
    row[tid + k * 256] = (hi << 16) | lo;
  }
}

// ---- LN1 -> bf16 q ----
__global__ __launch_bounds__(256) void k_ln1b(const float* __restrict__ x,
                                              const float* __restrict__ attn,
                                              const float* __restrict__ g,
                                              const float* __restrict__ be,
                                              ushort_t* __restrict__ qbf) {
  size_t base = (size_t)blockIdx.x * D_;
  int tid = threadIdx.x;
  __shared__ float rl[8];
  float v0 = x[base + tid] + attn[base + tid];
  float v1 = x[base + tid + 256] + attn[base + tid + 256];
  float s = v0 + v1, sq = v0 * v0 + v1 * v1;
  #pragma unroll
  for (int o = 32; o > 0; o >>= 1) { s += __shfl_down(s, o); sq += __shfl_down(sq, o); }
  int lane = tid & 63, wid = tid >> 6;
  if (lane == 0) { rl[wid] = s; rl[4 + wid] = sq; }
  __syncthreads();
  s = rl[0] + rl[1] + rl[2] + rl[3];
  sq = rl[4] + rl[5] + rl[6] + rl[7];
  float mean = s * (1.0f / 512.0f);
  float var = sq * (1.0f / 512.0f) - mean * mean;
  float rstd = rsqrtf(var + 1e-5f);
  qbf[base + tid]       = f2bfu((v0 - mean) * rstd * g[tid] + be[tid]);
  qbf[base + tid + 256] = f2bfu((v1 - mean) * rstd * g[tid + 256] + be[tid + 256]);
}

// ---- fast LN3: one block per (b,si); LDS transpose -> fully coalesced output ----
__global__ __launch_bounds__(256) void k_ln3_f(const float* __restrict__ y,
                                               const ushort_t* __restrict__ qbf,
                                               const float* __restrict__ g3,
                                               const float* __restrict__ be3,
                                               float* __restrict__ out) {
  __shared__ float ynorm[8][512];
  const int tid = threadIdx.x;
  const int w = tid >> 6, lane = tid & 63;
  #pragma unroll
  for (int rr = 0; rr < 2; ++rr) {
    int l = 2 * w + rr;
    size_t t = (size_t)blockIdx.x * 8 + l;
    float v[8];
    float s = 0.f, sq = 0.f;
    #pragma unroll
    for (int j = 0; j < 8; ++j) {
      int k = lane + 64 * j;
      v[j] = y[t * D_ + k] + bfu2f(qbf[t * D_ + k]);
      s += v[j]; sq += v[j] * v[j];
    }
    #pragma unroll
    for (int o = 32; o > 0; o >>= 1) { s += __shfl_down(s, o); sq += __shfl_down(sq, o); }
    s = __shfl(s, 0); sq = __shfl(sq, 0);
    float mean = s * (1.0f / 512.0f);
    float var = sq * (1.0f / 512.0f) - mean * mean;
    float rstd = rsqrtf(var + 1e-5f);
    #pragma unroll
    for (int j = 0; j < 8; ++j) {
      int k = lane + 64 * j;
      ynorm[l][k] = (v[j] - mean) * rstd * g3[k] + be3[k];
    }
  }
  __syncthreads();
  float* ob = out + (size_t)blockIdx.x * 4096;
  #pragma unroll
  for (int kk = 0; kk < 2; ++kk) {
    int k = tid * 2 + kk;
    float4 lo = make_float4(ynorm[0][k], ynorm[1][k], ynorm[2][k], ynorm[3][k]);
    float4 hi = make_float4(ynorm[4][k], ynorm[5][k], ynorm[6][k], ynorm[7][k]);
    *reinterpret_cast<float4*>(ob + (size_t)k * 8)     = lo;
    *reinterpret_cast<float4*>(ob + (size_t)k * 8 + 4) = hi;
  }
}

// ================= slow-path fp32 kernels (fallback only) =================
#define TS 64
#define KT 16
__global__ __launch_bounds__(256) void k_build_x_s(const float* __restrict__ lags,
                                                   float* __restrict__ x, int b_base) {
  int idx = blockIdx.x * 256 + threadIdx.x;
  int k = idx & (D_ - 1);
  int r = idx >> 9;
  int b = b_base + r / SQ;
  int t = r - (r / SQ) * SQ;
  int si = t >> 3, l = t & 7;
  size_t src = (((size_t)(b * S_ + si) * D_ + k) << 3) + l;
  x[idx] = lags[src];
}

__global__ __launch_bounds__(256) void k_scores(const float* __restrict__ x,
                                                float* __restrict__ sc, int b_base) {
  const float* A = x;
  float* C = sc;
  __shared__ float As[TS][KT + 1];
  __shared__ float Bs[TS][KT + 1];
  int tx = threadIdx.x & 15, ty = threadIdx.x >> 4;
  int j0 = blockIdx.x * TS, i0 = blockIdx.y * TS;
  float acc[4][4] = {};
  int lk = threadIdx.x & 15, lr = threadIdx.x >> 4;
  for (int k0 = 0; k0 < D_; k0 += KT) {
    #pragma unroll
    for (int it = 0; it < 4; ++it) {
      As[lr + 16 * it][lk] = A[(size_t)(i0 + lr + 16 * it) * D_ + k0 + lk];
      Bs[lr + 16 * it][lk] = A[(size_t)(j0 + lr + 16 * it) * D_ + k0 + lk];
    }
    __syncthreads();
    #pragma unroll
    for (int kk = 0; kk < KT; ++kk) {
      float a[4], bb[4];
      #pragma unroll
      for (int r = 0; r < 4; ++r) a[r] = As[ty * 4 + r][kk];
      #pragma unroll
      for (int c = 0; c < 4; ++c) bb[c] = Bs[tx * 4 + c][kk];
      #pragma unroll
      for (int r = 0; r < 4; ++r)
        #pragma unroll
        for (int c = 0; c < 4; ++c) acc[r][c] = fmaf(a[r], bb[c], acc[r][c]);
    }
    __syncthreads();
  }
  #pragma unroll
  for (int r = 0; r < 4; ++r) {
    float4 v = make_float4(acc[r][0]*SCALE_QK, acc[r][1]*SCALE_QK,
                           acc[r][2]*SCALE_QK, acc[r][3]*SCALE_QK);
    *reinterpret_cast<float4*>(&C[(size_t)(i0 + ty*4 + r) * SQ + j0 + tx*4]) = v;
  }
}

__global__ __launch_bounds__(256) void k_softmax(float* __restrict__ sc) {
  float* row = sc + (size_t)blockIdx.x * SQ;
  int tid = threadIdx.x;
  __shared__ float red[8];
  float m = -1e30f;
  for (int j = tid; j < SQ; j += 256) m = fmaxf(m, row[j]);
  #pragma unroll
  for (int o = 32; o > 0; o >>= 1) m = fmaxf(m, __shfl_down(m, o));
  if ((tid & 63) == 0) red[tid >> 6] = m;
  __syncthreads();
  m = fmaxf(fmaxf(red[0], red[1]), fmaxf(red[2], red[3]));
  __syncthreads();
  float ssum = 0.f;
  for (int j = tid; j < SQ; j += 256) { float e = expf(row[j] - m); row[j] = e; ssum += e; }
  #pragma unroll
  for (int o = 32; o > 0; o >>= 1) ssum += __shfl_down(ssum, o);
  if ((tid & 63) == 0) red[4 + (tid >> 6)] = ssum;
  __syncthreads();
  float inv = 1.0f / (red[4] + red[5] + red[6] + red[7]);
  for (int j = tid; j < SQ; j += 256) row[j] *= inv;
}

__global__ __launch_bounds__(256) void k_attn(const float* __restrict__ x,
                                              const float* __restrict__ sc,
                                              float* __restrict__ attn) {
  const float* X = x;
  const float* P = sc;
  float* O = attn;
  __shared__ float Ps[TS][KT + 1];
  __shared__ float Xs[KT][TS];
  int tx = threadIdx.x & 15, ty = threadIdx.x >> 4;
  int j0 = blockIdx.x * TS, i0 = blockIdx.y * TS;
  float acc[4][4] = {};
  int lk = threadIdx.x & 15, lr = threadIdx.x >> 4;
  int lc = threadIdx.x & 63, lrow = threadIdx.x >> 6;
  for (int k0 = 0; k0 < SQ; k0 += KT) {
    #pragma unroll
    for (int it = 0; it < 4; ++it)
      Ps[lr + 16 * it][lk] = P[(size_t)(i0 + lr + 16 * it) * SQ + k0 + lk];
    #pragma unroll
    for (int it = 0; it < 4; ++it)
      Xs[lrow + 4 * it][lc] = X[(size_t)(k0 + lrow + 4 * it) * D_ + j0 + lc];
    __syncthreads();
    #pragma unroll
    for (int kk = 0; kk < KT; ++kk) {
      float a[4], bb[4];
      #pragma unroll
      for (int r = 0; r < 4; ++r) a[r] = Ps[ty * 4 + r][kk];
      #pragma unroll
      for (int c = 0; c < 4; ++c) bb[c] = Xs[kk][tx * 4 + c];
      #pragma unroll
      for (int r = 0; r < 4; ++r)
        #pragma unroll
        for (int c = 0; c < 4; ++c) acc[r][c] = fmaf(a[r], bb[c], acc[r][c]);
    }
    __syncthreads();
  }
  #pragma unroll
  for (int r = 0; r < 4; ++r) {
    float4 v = make_float4(acc[r][0], acc[r][1], acc[r][2], acc[r][3]);
    *reinterpret_cast<float4*>(&O[(size_t)(i0 + ty*4 + r) * D_ + j0 + tx*4]) = v;
  }
}

__global__ __launch_bounds__(256) void k_ln1(const float* __restrict__ x,
                                             const float* __restrict__ attn,
                                             const float* __restrict__ g,
                                             const float* __restrict__ be,
                                             float* __restrict__ qout) {
  size_t base = (size_t)blockIdx.x * D_;
  int tid = threadIdx.x;
  __shared__ float rl[8];
  float v0 = x[base + tid] + attn[base + tid];
  float v1 = x[base + tid + 256] + attn[base + tid + 256];
  float s = v0 + v1, sq = v0 * v0 + v1 * v1;
  #pragma unroll
  for (int o = 32; o > 0; o >>= 1) { s += __shfl_down(s, o); sq += __shfl_down(sq, o); }
  int lane = tid & 63, wid = tid >> 6;
  if (lane == 0) { rl[wid] = s; rl[4 + wid] = sq; }
  __syncthreads();
  s = rl[0] + rl[1] + rl[2] + rl[3];
  sq = rl[4] + rl[5] + rl[6] + rl[7];
  float mean = s * (1.0f / 512.0f);
  float var = sq * (1.0f / 512.0f) - mean * mean;
  float rstd = rsqrtf(var + 1e-5f);
  qout[base + tid]       = (v0 - mean) * rstd * g[tid] + be[tid];
  qout[base + tid + 256] = (v1 - mean) * rstd * g[tid + 256] + be[tid + 256];
}

__global__ __launch_bounds__(256, 2) void k_ffn(
    const float* __restrict__ q,
    const float* __restrict__ W1, const float* __restrict__ b1,
    const float* __restrict__ W2, const float* __restrict__ b2,
    const float* __restrict__ g3, const float* __restrict__ be3,
    float* __restrict__ out, int row_base)
{
  __shared__ float qs[8][D_];
  __shared__ float mid[8][H_];
  const int tid = threadIdx.x;
  const int row0 = blockIdx.x * 8;
  for (int idx = tid; idx < 8 * D_; idx += 256)
    qs[idx >> 9][idx & (D_ - 1)] = q[(size_t)row0 * D_ + idx];
  __syncthreads();
  float acc[8][8];
  {
    float4 bA = *reinterpret_cast<const float4*>(b1 + (tid << 3));
    float4 bB = *reinterpret_cast<const float4*>(b1 + (tid << 3) + 4);
    float bv[8] = {bA.x, bA.y, bA.z, bA.w, bB.x, bB.y, bB.z, bB.w};
    #pragma unroll
    for (int jj = 0; jj < 8; ++jj)
      #pragma unroll
      for (int r = 0; r < 8; ++r) acc[jj][r] = bv[jj];
  }
  for (int k4 = 0; k4 < D_ / 4; ++k4) {
    float4 qv[8];
    #pragma unroll
    for (int r = 0; r < 8; ++r)
      qv[r] = *reinterpret_cast<const float4*>(&qs[r][k4 << 2]);
    #pragma unroll
    for (int kk = 0; kk < 4; ++kk) {
      const int k = (k4 << 2) + kk;
      float4 wA = *reinterpret_cast<const float4*>(W1 + (size_t)k * H_ + (tid << 3));
      float4 wB = *reinterpret_cast<const float4*>(W1 + (size_t)k * H_ + (tid << 3) + 4);
      float wv[8] = {wA.x, wA.y, wA.z, wA.w, wB.x, wB.y, wB.z, wB.w};
      #pragma unroll
      for (int r = 0; r < 8; ++r) {
        float qk = (kk == 0) ? qv[r].x : (kk == 1) ? qv[r].y : (kk == 2) ? qv[r].z : qv[r].w;
        #pragma unroll
        for (int jj = 0; jj < 8; ++jj) acc[jj][r] = fmaf(qk, wv[jj], acc[jj][r]);
      }
    }
  }
  #pragma unroll
  for (int jj = 0; jj < 8; ++jj)
    #pragma unroll
    for (int r = 0; r < 8; ++r) {
      float v = acc[jj][r];
      mid[r][(tid << 3) + jj] = 0.5f * v * (1.0f + erff(v * 0.70710678118654752f));
    }
  __syncthreads();
  float acc2[8][2];
  {
    float b20 = b2[tid << 1], b21 = b2[(tid << 1) + 1];
    #pragma unroll
    for (int r = 0; r < 8; ++r) { acc2[r][0] = b20; acc2[r][1] = b21; }
  }
  for (int j4 = 0; j4 < H_ / 4; ++j4) {
    float4 mv[8];
    #pragma unroll
    for (int r = 0; r < 8; ++r)
      mv[r] = *reinterpret_cast<const float4*>(&mid[r][j4 << 2]);
    #pragma unroll
    for (int kk = 0; kk < 4; ++kk) {
      const int j = (j4 << 2) + kk;
      float2 wv = *reinterpret_cast<const float2*>(W2 + (size_t)j * D_ + (tid << 1));
      #pragma unroll
      for (int r = 0; r < 8; ++r) {
        float m = (kk == 0) ? mv[r].x : (kk == 1) ? mv[r].y : (kk == 2) ? mv[r].z : mv[r].w;
        acc2[r][0] = fmaf(m, wv.x, acc2[r][0]);
        acc2[r][1] = fmaf(m, wv.y, acc2[r][1]);
      }
    }
  }
  __syncthreads();
  float* ys = &mid[0][0];
  #pragma unroll
  for (int r = 0; r < 8; ++r) {
    ys[r * D_ + (tid << 1)]     = qs[r][(tid << 1)]     + acc2[r][0];
    ys[r * D_ + (tid << 1) + 1] = qs[r][(tid << 1) + 1] + acc2[r][1];
  }
  __syncthreads();
  float g3a = g3[tid],  g3b = g3[tid + 256];
  float be3a = be3[tid], be3b = be3[tid + 256];
  float* rl = &qs[0][0];
  for (int r = 0; r < 8; ++r) {
    float v0 = ys[r * D_ + tid], v1 = ys[r * D_ + tid + 256];
    float s = v0 + v1, sq = v0 * v0 + v1 * v1;
    #pragma unroll
    for (int o = 32; o > 0; o >>= 1) { s += __shfl_down(s, o); sq += __shfl_down(sq, o); }
    int lane = tid & 63, wid = tid >> 6;
    if (lane == 0) { rl[wid] = s; rl[4 + wid] = sq; }
    __syncthreads();
    s = rl[0] + rl[1] + rl[2] + rl[3];
    sq = rl[4] + rl[5] + rl[6] + rl[7];
    __syncthreads();
    float mean = s * (1.0f / 512.0f);
    float var = sq * (1.0f / 512.0f) - mean * mean;
    float rstd = rsqrtf(var + 1e-5f);
    int t = row_base + row0 + r;
    int b = t / SQ, tt = t - b * SQ;
    int si = tt >> 3, l = tt & 7;
    size_t ob = (((size_t)(b * S_ + si) * D_) << 3) + l;
    out[ob + ((size_t)tid << 3)]         = (v0 - mean) * rstd * g3a + be3a;
    out[ob + ((size_t)(tid + 256) << 3)] = (v1 - mean) * rstd * g3b + be3b;
  }
}

extern "C" void kernel_launch(void* const* d_in, const int* in_sizes, int n_in,
                              void* d_out, int out_size, void* d_ws, size_t ws_size,
                              hipStream_t stream) {
  const float* lags   = (const float*)d_in[0];
  const float* gamma1 = (const float*)d_in[1];
  const float* beta1  = (const float*)d_in[2];
  const float* W1     = (const float*)d_in[3];
  const float* b1     = (const float*)d_in[4];
  const float* W2     = (const float*)d_in[5];
  const float* b2     = (const float*)d_in[6];
  const float* g3     = (const float*)d_in[7];
  const float* be3    = (const float*)d_in[8];
  float* out = (float*)d_out;

  float* ws = (float*)d_ws;
  const size_t NX  = (size_t)B_ * SQ * D_;   // 6,291,456
  const size_t NXB = (size_t)SQ * D_;        //   786,432
  const size_t NS  = (size_t)SQ * SQ;        // 2,359,296

  const size_t need_full = (3 * NX + 8 * NS) * sizeof(float);  // ~151 MB (proven available)

  if (ws_size >= need_full) {
    // ---- fast path layout (~130 MB) ----
    float* x        = ws;                                   // NX f32
    float* attn     = x + NX;                               // NX f32 (later: y)
    ushort_t* q_bf  = (ushort_t*)(attn + NX);               // NX us
    ushort_t* w1t   = q_bf + NX;                            // H*D us
    ushort_t* w2t   = w1t + (size_t)H_ * D_;                // H*D us
    ushort_t* region = w2t + (size_t)H_ * D_;               // 8*NS + 2*NX us
    ushort_t* sc_bf = region;                               // scores / P, bf16, in-place
    ushort_t* x_bf  = region + 8 * NS;
    ushort_t* xT_bf = x_bf + NX;
    ushort_t* mid_bf = region;                              // aliases dead sc/x_bf/xT_bf

    k_build_x_f<<<dim3(B_ * S_), 256, 0, stream>>>(lags, x, x_bf, xT_bf);
    k_wt<<<dim3(H_ / 64, D_ / 64), 256, 0, stream>>>(W1, w1t, D_, H_);
    k_wt<<<dim3(D_ / 64, H_ / 64), 256, 0, stream>>>(W2, w2t, H_, D_);
    // scores = scale * X X^T -> bf16
    k_gemm<2><<<dim3(SQ / 128, SQ / 128, B_), 256, 0, stream>>>(
        x_bf, x_bf, nullptr, sc_bf, SQ, D_, SQ, NXB, NXB, NS, SCALE_QK);
    k_softmax_bf<<<dim3(SQ, 1, B_), 256, 0, stream>>>(sc_bf);
    // attn = P @ X -> f32
    k_gemm<3><<<dim3(D_ / 128, SQ / 128, B_), 256, 0, stream>>>(
        sc_bf, xT_bf, nullptr, attn, SQ, SQ, D_, NS, NXB, NXB, 1.0f);
    k_ln1b<<<dim3(NROW), 256, 0, stream>>>(x, attn, gamma1, beta1, q_bf);
    // mid = gelu(q @ W1 + b1) -> bf16
    k_gemm<0><<<dim3(H_ / 128, NROW / 128, 1), 256, 0, stream>>>(
        q_bf, w1t, b1, mid_bf, NROW, D_, H_, 0, 0, 0, 1.0f);
    // y = mid @ W2 + b2 -> f32 (attn buffer)
    k_gemm<1><<<dim3(D_ / 128, NROW / 128, 1), 256, 0, stream>>>(
        mid_bf, w2t, b2, attn, NROW, H_, D_, 0, 0, 0, 1.0f);
    k_ln3_f<<<dim3(B_ * S_), 256, 0, stream>>>(attn, q_bf, g3, be3, out);
  } else {
    // ---- minimal-footprint fallback (fp32, per-batch) ----
    float* xb   = ws;
    float* sc   = xb + NXB;
    float* atb  = sc + NS;
    float* qb   = atb + NXB;
    for (int b = 0; b < B_; ++b) {
      k_build_x_s<<<dim3((unsigned)(NXB / 256)), 256, 0, stream>>>(lags, xb, b);
      k_scores<<<dim3(SQ / TS, SQ / TS, 1), 256, 0, stream>>>(xb, sc, b);
      k_softmax<<<dim3(SQ, 1, 1), 256, 0, stream>>>(sc);
      k_attn<<<dim3(D_ / TS, SQ / TS, 1), 256, 0, stream>>>(xb, sc, atb);
      k_ln1<<<dim3(SQ), 256, 0, stream>>>(xb, atb, gamma1, beta1, qb);
      k_ffn<<<dim3(SQ / 8), 256, 0, stream>>>(qb, W1, b1, W2, b2, g3, be3, out, b * SQ);
    }
  }
}

// Round 5
// 302.289 us; speedup vs baseline: 1.0048x; 1.0048x over previous
//
#include <hip/hip_runtime.h>
#include <hip/hip_bf16.h>
#include <math.h>

#define B_ 8
#define S_ 192
#define D_ 512
#define L_ 8
#define SQ 1536   // S_*L_
#define H_ 2048
#define NROW (B_*SQ)   // 12288
#define SCALE_QK 0.04419417382415922f  // 1/sqrt(512)

typedef unsigned short ushort_t;
typedef unsigned int uint_t;
typedef __attribute__((ext_vector_type(8))) short bf16x8;
typedef __attribute__((ext_vector_type(4))) float f32x4;

__device__ __forceinline__ float bfu2f(ushort_t u) { return __uint_as_float((unsigned)u << 16); }
__device__ __forceinline__ ushort_t f2bfu(float f) {
  __hip_bfloat16 h = __float2bfloat16(f);
  return *reinterpret_cast<ushort_t*>(&h);
}

// tanh-form GELU: 0.5x(1+tanh(0.79788456(x+0.044715x^3))), max |err| ~3e-4.
__device__ __forceinline__ float gelu_tanh(float x) {
  float x2 = x * x;
  float u2 = x * fmaf(0.0713548162f, x2, 1.5957691216f);
  float e = __expf(u2);                       // e^(2u)
  float r = fmaf(-2.0f, __builtin_amdgcn_rcpf(e + 1.0f), 1.0f);  // tanh(u)
  float hx = 0.5f * x;
  return fmaf(hx, r, hx);
}

// async global->LDS, 16B per lane; LDS dest = wave-uniform base + lane*16
__device__ __forceinline__ void gl_lds16(const ushort_t* g, ushort_t* l) {
  __builtin_amdgcn_global_load_lds(
      (const __attribute__((address_space(1))) unsigned int*)g,
      (__attribute__((address_space(3))) unsigned int*)l, 16, 0, 0);
}

// counted vmcnt wait: leaves N newest VMEM ops in flight (T4).
#define VMWAIT(N) asm volatile("s_waitcnt vmcnt(" #N ")" ::: "memory")

// ---- fast build x: one block per (b,si); coalesced read of 4096 floats, LDS transpose.
// Emits x (f32), x_bf (bf16) and xT_bf ([B][D][SQ]) directly.
__global__ __launch_bounds__(256) void k_build_x_f(const float* __restrict__ lags,
                                                   float* __restrict__ x,
                                                   ushort_t* __restrict__ x_bf,
                                                   ushort_t* __restrict__ xT) {
  __shared__ float tile[512][9];
  const int tid = threadIdx.x;
  const float* in = lags + (size_t)blockIdx.x * 4096;
  #pragma unroll
  for (int it = 0; it < 4; ++it) {
    int f = (tid + it * 256) * 4;
    float4 v = *reinterpret_cast<const float4*>(in + f);
    int k = f >> 3, l0 = f & 7;
    tile[k][l0] = v.x; tile[k][l0 + 1] = v.y; tile[k][l0 + 2] = v.z; tile[k][l0 + 3] = v.w;
  }
  __syncthreads();
  const int l = tid >> 5, kbase = tid & 31;
  const size_t r = (size_t)blockIdx.x * 8 + l;
  #pragma unroll
  for (int j = 0; j < 16; ++j) {
    int k = kbase + 32 * j;
    float v = tile[k][l];
    x[r * D_ + k] = v;
    x_bf[r * D_ + k] = f2bfu(v);
  }
  const int b = blockIdx.x / S_, si = blockIdx.x - b * S_;
  #pragma unroll
  for (int dd = 0; dd < 2; ++dd) {
    int d = tid + dd * 256;
    uint_t pk[4];
    #pragma unroll
    for (int j = 0; j < 4; ++j) {
      uint_t lo = f2bfu(tile[d][2 * j]);
      uint_t hi = f2bfu(tile[d][2 * j + 1]);
      pk[j] = (hi << 16) | lo;
    }
    uint_t* dst = (uint_t*)(xT + ((size_t)b * D_ + d) * SQ + si * 8);
    *reinterpret_cast<uint4*>(dst) = make_uint4(pk[0], pk[1], pk[2], pk[3]);
  }
}

// ---- cast + transpose weights: W[K][N] fp32 -> Wt[N][K] bf16 ----
__global__ __launch_bounds__(256) void k_wt(const float* __restrict__ W,
                                            ushort_t* __restrict__ Wt,
                                            int K, int N) {
  __shared__ ushort_t tile[64][65];
  int n0 = blockIdx.x * 64, k0 = blockIdx.y * 64;
  for (int i = threadIdx.x; i < 4096; i += 256) {
    int kk = i >> 6, nn = i & 63;
    tile[nn][kk] = f2bfu(W[(size_t)(k0 + kk) * N + n0 + nn]);
  }
  __syncthreads();
  for (int i = threadIdx.x; i < 4096; i += 256) {
    int nn = i >> 6, kk = i & 63;
    Wt[(size_t)(n0 + nn) * K + k0 + kk] = tile[nn][kk];
  }
}

// ---- bf16 MFMA GEMM v2: 256x128 tile, 512 thr (8 waves, 4M x 2N), BK=64,
// 16x16x32 MFMA, THREE-deep LDS tile rotation, counted vmcnt, 1 barrier/tile.
//   C[M,N] = A[M,K] @ Bt[N,K]^T
// MODE 0: +bias, gelu -> bf16 | 1: +bias -> f32 | 2: *scale -> bf16 | 3: -> f32
//
// Pipeline invariant (3 buffers, tile t uses buf t%3):
//   iter t: VMWAIT(6) [stage(t) landed; stage(t+1)'s 6 loads stay in flight];
//           s_barrier [all waves' tile t-1 LDS reads complete];
//           STAGE(t+2 -> buf (t+2)%3) [that buf's readers were tile t-1: done];
//           COMPUTE(buf t%3).
// Issue->wait distance = 2 full tiles (~>=900cy): HBM latency fully covered;
// vmcnt never drains to 0 mid-loop (only for the final tile).
// LDS layout (zero-conflict, verified r0-r2): row r stride 64 ushorts; 8-ushort
// chunk p holds global chunk p ^ (r&7); frag read csel = ((kk*4+quad)^(l15&7))*8.
// Requires M%256==0, N%128==0, K%64==0, K/64>=4, grid.x*grid.y % 8 == 0.
template<int MODE>
__global__ __launch_bounds__(512) void k_gemm2(const ushort_t* __restrict__ A,
                                               const ushort_t* __restrict__ Bt,
                                               const float* __restrict__ bias,
                                               void* __restrict__ Cout,
                                               int M, int K, int N,
                                               size_t sAz, size_t sBz, size_t sCz,
                                               float scale) {
  A  += (size_t)blockIdx.z * sAz;
  Bt += (size_t)blockIdx.z * sBz;
  __shared__ ushort_t As0[256 * 64];   // 32 KB each (A: 256 rows)
  __shared__ ushort_t As1[256 * 64];
  __shared__ ushort_t As2[256 * 64];
  __shared__ ushort_t Bs0[128 * 64];   // 16 KB each (B: 128 rows)
  __shared__ ushort_t Bs1[128 * 64];
  __shared__ ushort_t Bs2[128 * 64];   // total 144 KB -> 1 block/CU

  // XCD-aware bijective swizzle (T1): contiguous grid chunk per XCD.
  const int gx = gridDim.x;
  const int nwg = gx * gridDim.y;
  int lin = blockIdx.y * gx + blockIdx.x;
  lin = (lin & 7) * (nwg >> 3) + (lin >> 3);       // nwg % 8 == 0 at all call sites
  const int n0 = (lin % gx) * 128;
  const int m0 = (lin / gx) * 256;

  const int tid = threadIdx.x;
  const int w = tid >> 6, lane = tid & 63;
  const int wm = w >> 1, wn = w & 1;               // 4 x 2 wave grid, 64x64 out each
  const int l15 = lane & 15, quad = lane >> 4;
  const int lrow8 = lane >> 3;                     // staging row within 8-row group
  const int cg = ((lane & 7) ^ lrow8) * 8;         // swizzled global source chunk
  const int xsw = l15 & 7;                         // fragment-read xor
  const size_t sK64 = (size_t)64 * K;

  f32x4 acc[4][4];
  if (MODE <= 1) {
    #pragma unroll
    for (int nj = 0; nj < 4; ++nj) {
      float bv = bias[n0 + wn * 64 + nj * 16 + l15];
      #pragma unroll
      for (int mi = 0; mi < 4; ++mi) acc[mi][nj] = (f32x4){bv, bv, bv, bv};
    }
  } else {
    #pragma unroll
    for (int nj = 0; nj < 4; ++nj)
      #pragma unroll
      for (int mi = 0; mi < 4; ++mi) acc[mi][nj] = (f32x4){0.f, 0.f, 0.f, 0.f};
  }

  // per-thread staging source bases (row = w*8 + lrow8 within each 64-row group)
  const ushort_t* pA = A  + (size_t)(m0 + w * 8 + lrow8) * K + cg;
  const ushort_t* pB = Bt + (size_t)(n0 + w * 8 + lrow8) * K + cg;
  // wave-uniform LDS staging bases: group j starts at row j*64 + w*8
  const int lb = (w * 8) * 64;

#define STAGE(TT, AS, BS) do {                                              \
    const size_t ko_ = (size_t)(TT) * 64;                                   \
    gl_lds16(pA + ko_,             &AS[lb]);                                \
    gl_lds16(pA + ko_ +     sK64,  &AS[lb + 64 * 64]);                      \
    gl_lds16(pA + ko_ + 2 * sK64,  &AS[lb + 128 * 64]);                     \
    gl_lds16(pA + ko_ + 3 * sK64,  &AS[lb + 192 * 64]);                     \
    gl_lds16(pB + ko_,             &BS[lb]);                                \
    gl_lds16(pB + ko_ +     sK64,  &BS[lb + 64 * 64]);                      \
  } while (0)

#define COMPUTE(AS, BS) do {                                                \
    _Pragma("unroll")                                                       \
    for (int kk_ = 0; kk_ < 2; ++kk_) {                                     \
      const int csel_ = ((kk_ * 4 + quad) ^ xsw) * 8;                       \
      bf16x8 af_[4], bf_[4];                                                \
      _Pragma("unroll")                                                     \
      for (int mi_ = 0; mi_ < 4; ++mi_)                                     \
        af_[mi_] = *reinterpret_cast<const bf16x8*>(                        \
            &AS[(wm * 64 + mi_ * 16 + l15) * 64 + csel_]);                  \
      _Pragma("unroll")                                                     \
      for (int nj_ = 0; nj_ < 4; ++nj_)                                     \
        bf_[nj_] = *reinterpret_cast<const bf16x8*>(                        \
            &BS[(wn * 64 + nj_ * 16 + l15) * 64 + csel_]);                  \
      _Pragma("unroll")                                                     \
      for (int mi_ = 0; mi_ < 4; ++mi_)                                     \
        _Pragma("unroll")                                                   \
        for (int nj_ = 0; nj_ < 4; ++nj_)                                   \
          acc[mi_][nj_] = __builtin_amdgcn_mfma_f32_16x16x32_bf16(          \
              af_[mi_], bf_[nj_], acc[mi_][nj_], 0, 0, 0);                  \
    }                                                                       \
  } while (0)

#define STEP(TT, CA, CB, NA, NB) do {                                       \
    if ((TT) < nt) {                                                        \
      if ((TT) == nt - 1) { VMWAIT(0); } else { VMWAIT(6); }                \
      __builtin_amdgcn_s_barrier();                                         \
      if ((TT) + 2 < nt) STAGE((TT) + 2, NA, NB);                           \
      COMPUTE(CA, CB);                                                      \
    }                                                                       \
  } while (0)

  const int nt = K >> 6;   // >= 8 at all call sites
  // prologue: tiles 0 and 1 in flight (12 loads/thread)
  STAGE(0, As0, Bs0);
  STAGE(1, As1, Bs1);
  for (int t = 0; t < nt; t += 3) {
    STEP(t,     As0, Bs0, As2, Bs2);   // compute buf0, stage t+2 -> buf2
    STEP(t + 1, As1, Bs1, As0, Bs0);   // compute buf1, stage t+3 -> buf0
    STEP(t + 2, As2, Bs2, As1, Bs1);   // compute buf2, stage t+4 -> buf1
  }

#undef STAGE
#undef COMPUTE
#undef STEP

  ushort_t* Cb = (ushort_t*)Cout + (size_t)blockIdx.z * sCz;
  float*    Cf = (float*)Cout    + (size_t)blockIdx.z * sCz;
  #pragma unroll
  for (int mi = 0; mi < 4; ++mi)
    #pragma unroll
    for (int nj = 0; nj < 4; ++nj) {
      int gc = n0 + wn * 64 + nj * 16 + l15;
      #pragma unroll
      for (int r = 0; r < 4; ++r) {
        int gr = m0 + wm * 64 + mi * 16 + quad * 4 + r;
        float v = acc[mi][nj][r];
        if (MODE == 0) {
          Cb[(size_t)gr * N + gc] = f2bfu(gelu_tanh(v));
        } else if (MODE == 1) {
          Cf[(size_t)gr * N + gc] = v;
        } else if (MODE == 2) {
          Cb[(size_t)gr * N + gc] = f2bfu(v * scale);
        } else {
          Cf[(size_t)gr * N + gc] = v;
        }
      }
    }
}

// ---- softmax rows in place, bf16 storage (uint-packed), fp32 math ----
__global__ __launch_bounds__(256) void k_softmax_bf(ushort_t* __restrict__ sc) {
  uint_t* row = (uint_t*)(sc + (size_t)blockIdx.z * SQ * SQ + (size_t)blockIdx.x * SQ);
  int tid = threadIdx.x;
  __shared__ float red[8];
  float v[6];
  float m = -1e30f;
  #pragma unroll
  for (int k = 0; k < 3; ++k) {
    uint_t u = row[tid + k * 256];
    v[2*k]   = __uint_as_float(u << 16);
    v[2*k+1] = __uint_as_float(u & 0xffff0000u);
    m = fmaxf(m, fmaxf(v[2*k], v[2*k+1]));
  }
  #pragma unroll
  for (int o = 32; o > 0; o >>= 1) m = fmaxf(m, __shfl_down(m, o));
  if ((tid & 63) == 0) red[tid >> 6] = m;
  __syncthreads();
  m = fmaxf(fmaxf(red[0], red[1]), fmaxf(red[2], red[3]));
  __syncthreads();
  float ssum = 0.f;
  #pragma unroll
  for (int k = 0; k < 6; ++k) { v[k] = expf(v[k] - m); ssum += v[k]; }
  #pragma unroll
  for (int o = 32; o > 0; o >>= 1) ssum += __shfl_down(ssum, o);
  if ((tid & 63) == 0) red[4 + (tid >> 6)] = ssum;
  __syncthreads();
  float inv = 1.0f / (red[4] + red[5] + red[6] + red[7]);
  #pragma unroll
  for (int k = 0; k < 3; ++k) {
    uint_t lo = f2bfu(v[2*k] * inv);
    uint_t hi = f2bfu(v[2*k+1] * inv);
    row[tid + k * 256] = (hi << 16) | lo;
  }
}

// ---- LN1 -> bf16 q ----
__global__ __launch_bounds__(256) void k_ln1b(const float* __restrict__ x,
                                              const float* __restrict__ attn,
                                              const float* __restrict__ g,
                                              const float* __restrict__ be,
                                              ushort_t* __restrict__ qbf) {
  size_t base = (size_t)blockIdx.x * D_;
  int tid = threadIdx.x;
  __shared__ float rl[8];
  float v0 = x[base + tid] + attn[base + tid];
  float v1 = x[base + tid + 256] + attn[base + tid + 256];
  float s = v0 + v1, sq = v0 * v0 + v1 * v1;
  #pragma unroll
  for (int o = 32; o > 0; o >>= 1) { s += __shfl_down(s, o); sq += __shfl_down(sq, o); }
  int lane = tid & 63, wid = tid >> 6;
  if (lane == 0) { rl[wid] = s; rl[4 + wid] = sq; }
  __syncthreads();
  s = rl[0] + rl[1] + rl[2] + rl[3];
  sq = rl[4] + rl[5] + rl[6] + rl[7];
  float mean = s * (1.0f / 512.0f);
  float var = sq * (1.0f / 512.0f) - mean * mean;
  float rstd = rsqrtf(var + 1e-5f);
  qbf[base + tid]       = f2bfu((v0 - mean) * rstd * g[tid] + be[tid]);
  qbf[base + tid + 256] = f2bfu((v1 - mean) * rstd * g[tid + 256] + be[tid + 256]);
}

// ---- fast LN3: one block per (b,si); LDS transpose -> fully coalesced output ----
__global__ __launch_bounds__(256) void k_ln3_f(const float* __restrict__ y,
                                               const ushort_t* __restrict__ qbf,
                                               const float* __restrict__ g3,
                                               const float* __restrict__ be3,
                                               float* __restrict__ out) {
  __shared__ float ynorm[8][512];
  const int tid = threadIdx.x;
  const int w = tid >> 6, lane = tid & 63;
  #pragma unroll
  for (int rr = 0; rr < 2; ++rr) {
    int l = 2 * w + rr;
    size_t t = (size_t)blockIdx.x * 8 + l;
    float v[8];
    float s = 0.f, sq = 0.f;
    #pragma unroll
    for (int j = 0; j < 8; ++j) {
      int k = lane + 64 * j;
      v[j] = y[t * D_ + k] + bfu2f(qbf[t * D_ + k]);
      s += v[j]; sq += v[j] * v[j];
    }
    #pragma unroll
    for (int o = 32; o > 0; o >>= 1) { s += __shfl_down(s, o); sq += __shfl_down(sq, o); }
    s = __shfl(s, 0); sq = __shfl(sq, 0);
    float mean = s * (1.0f / 512.0f);
    float var = sq * (1.0f / 512.0f) - mean * mean;
    float rstd = rsqrtf(var + 1e-5f);
    #pragma unroll
    for (int j = 0; j < 8; ++j) {
      int k = lane + 64 * j;
      ynorm[l][k] = (v[j] - mean) * rstd * g3[k] + be3[k];
    }
  }
  __syncthreads();
  float* ob = out + (size_t)blockIdx.x * 4096;
  #pragma unroll
  for (int kk = 0; kk < 2; ++kk) {
    int k = tid * 2 + kk;
    float4 lo = make_float4(ynorm[0][k], ynorm[1][k], ynorm[2][k], ynorm[3][k]);
    float4 hi = make_float4(ynorm[4][k], ynorm[5][k], ynorm[6][k], ynorm[7][k]);
    *reinterpret_cast<float4*>(ob + (size_t)k * 8)     = lo;
    *reinterpret_cast<float4*>(ob + (size_t)k * 8 + 4) = hi;
  }
}

// ================= slow-path fp32 kernels (fallback only) =================
#define TS 64
#define KT 16
__global__ __launch_bounds__(256) void k_build_x_s(const float* __restrict__ lags,
                                                   float* __restrict__ x, int b_base) {
  int idx = blockIdx.x * 256 + threadIdx.x;
  int k = idx & (D_ - 1);
  int r = idx >> 9;
  int b = b_base + r / SQ;
  int t = r - (r / SQ) * SQ;
  int si = t >> 3, l = t & 7;
  size_t src = (((size_t)(b * S_ + si) * D_ + k) << 3) + l;
  x[idx] = lags[src];
}

__global__ __launch_bounds__(256) void k_scores(const float* __restrict__ x,
                                                float* __restrict__ sc, int b_base) {
  const float* A = x;
  float* C = sc;
  __shared__ float As[TS][KT + 1];
  __shared__ float Bs[TS][KT + 1];
  int tx = threadIdx.x & 15, ty = threadIdx.x >> 4;
  int j0 = blockIdx.x * TS, i0 = blockIdx.y * TS;
  float acc[4][4] = {};
  int lk = threadIdx.x & 15, lr = threadIdx.x >> 4;
  for (int k0 = 0; k0 < D_; k0 += KT) {
    #pragma unroll
    for (int it = 0; it < 4; ++it) {
      As[lr + 16 * it][lk] = A[(size_t)(i0 + lr + 16 * it) * D_ + k0 + lk];
      Bs[lr + 16 * it][lk] = A[(size_t)(j0 + lr + 16 * it) * D_ + k0 + lk];
    }
    __syncthreads();
    #pragma unroll
    for (int kk = 0; kk < KT; ++kk) {
      float a[4], bb[4];
      #pragma unroll
      for (int r = 0; r < 4; ++r) a[r] = As[ty * 4 + r][kk];
      #pragma unroll
      for (int c = 0; c < 4; ++c) bb[c] = Bs[tx * 4 + c][kk];
      #pragma unroll
      for (int r = 0; r < 4; ++r)
        #pragma unroll
        for (int c = 0; c < 4; ++c) acc[r][c] = fmaf(a[r], bb[c], acc[r][c]);
    }
    __syncthreads();
  }
  #pragma unroll
  for (int r = 0; r < 4; ++r) {
    float4 v = make_float4(acc[r][0]*SCALE_QK, acc[r][1]*SCALE_QK,
                           acc[r][2]*SCALE_QK, acc[r][3]*SCALE_QK);
    *reinterpret_cast<float4*>(&C[(size_t)(i0 + ty*4 + r) * SQ + j0 + tx*4]) = v;
  }
}

__global__ __launch_bounds__(256) void k_softmax(float* __restrict__ sc) {
  float* row = sc + (size_t)blockIdx.x * SQ;
  int tid = threadIdx.x;
  __shared__ float red[8];
  float m = -1e30f;
  for (int j = tid; j < SQ; j += 256) m = fmaxf(m, row[j]);
  #pragma unroll
  for (int o = 32; o > 0; o >>= 1) m = fmaxf(m, __shfl_down(m, o));
  if ((tid & 63) == 0) red[tid >> 6] = m;
  __syncthreads();
  m = fmaxf(fmaxf(red[0], red[1]), fmaxf(red[2], red[3]));
  __syncthreads();
  float ssum = 0.f;
  for (int j = tid; j < SQ; j += 256) { float e = expf(row[j] - m); row[j] = e; ssum += e; }
  #pragma unroll
  for (int o = 32; o > 0; o >>= 1) ssum += __shfl_down(ssum, o);
  if ((tid & 63) == 0) red[4 + (tid >> 6)] = ssum;
  __syncthreads();
  float inv = 1.0f / (red[4] + red[5] + red[6] + red[7]);
  for (int j = tid; j < SQ; j += 256) row[j] *= inv;
}

__global__ __launch_bounds__(256) void k_attn(const float* __restrict__ x,
                                              const float* __restrict__ sc,
                                              float* __restrict__ attn) {
  const float* X = x;
  const float* P = sc;
  float* O = attn;
  __shared__ float Ps[TS][KT + 1];
  __shared__ float Xs[KT][TS];
  int tx = threadIdx.x & 15, ty = threadIdx.x >> 4;
  int j0 = blockIdx.x * TS, i0 = blockIdx.y * TS;
  float acc[4][4] = {};
  int lk = threadIdx.x & 15, lr = threadIdx.x >> 4;
  int lc = threadIdx.x & 63, lrow = threadIdx.x >> 6;
  for (int k0 = 0; k0 < SQ; k0 += KT) {
    #pragma unroll
    for (int it = 0; it < 4; ++it)
      Ps[lr + 16 * it][lk] = P[(size_t)(i0 + lr + 16 * it) * SQ + k0 + lk];
    #pragma unroll
    for (int it = 0; it < 4; ++it)
      Xs[lrow + 4 * it][lc] = X[(size_t)(k0 + lrow + 4 * it) * D_ + j0 + lc];
    __syncthreads();
    #pragma unroll
    for (int kk = 0; kk < KT; ++kk) {
      float a[4], bb[4];
      #pragma unroll
      for (int r = 0; r < 4; ++r) a[r] = Ps[ty * 4 + r][kk];
      #pragma unroll
      for (int c = 0; c < 4; ++c) bb[c] = Xs[kk][tx * 4 + c];
      #pragma unroll
      for (int r = 0; r < 4; ++r)
        #pragma unroll
        for (int c = 0; c < 4; ++c) acc[r][c] = fmaf(a[r], bb[c], acc[r][c]);
    }
    __syncthreads();
  }
  #pragma unroll
  for (int r = 0; r < 4; ++r) {
    float4 v = make_float4(acc[r][0], acc[r][1], acc[r][2], acc[r][3]);
    *reinterpret_cast<float4*>(&O[(size_t)(i0 + ty*4 + r) * D_ + j0 + tx*4]) = v;
  }
}

__global__ __launch_bounds__(256) void k_ln1(const float* __restrict__ x,
                                             const float* __restrict__ attn,
                                             const float* __restrict__ g,
                                             const float* __restrict__ be,
                                             float* __restrict__ qout) {
  size_t base = (size_t)blockIdx.x * D_;
  int tid = threadIdx.x;
  __shared__ float rl[8];
  float v0 = x[base + tid] + attn[base + tid];
  float v1 = x[base + tid + 256] + attn[base + tid + 256];
  float s = v0 + v1, sq = v0 * v0 + v1 * v1;
  #pragma unroll
  for (int o = 32; o > 0; o >>= 1) { s += __shfl_down(s, o); sq += __shfl_down(sq, o); }
  int lane = tid & 63, wid = tid >> 6;
  if (lane == 0) { rl[wid] = s; rl[4 + wid] = sq; }
  __syncthreads();
  s = rl[0] + rl[1] + rl[2] + rl[3];
  sq = rl[4] + rl[5] + rl[6] + rl[7];
  float mean = s * (1.0f / 512.0f);
  float var = sq * (1.0f / 512.0f) - mean * mean;
  float rstd = rsqrtf(var + 1e-5f);
  qout[base + tid]       = (v0 - mean) * rstd * g[tid] + be[tid];
  qout[base + tid + 256] = (v1 - mean) * rstd * g[tid + 256] + be[tid + 256];
}

__global__ __launch_bounds__(256, 2) void k_ffn(
    const float* __restrict__ q,
    const float* __restrict__ W1, const float* __restrict__ b1,
    const float* __restrict__ W2, const float* __restrict__ b2,
    const float* __restrict__ g3, const float* __restrict__ be3,
    float* __restrict__ out, int row_base)
{
  __shared__ float qs[8][D_];
  __shared__ float mid[8][H_];
  const int tid = threadIdx.x;
  const int row0 = blockIdx.x * 8;
  for (int idx = tid; idx < 8 * D_; idx += 256)
    qs[idx >> 9][idx & (D_ - 1)] = q[(size_t)row0 * D_ + idx];
  __syncthreads();
  float acc[8][8];
  {
    float4 bA = *reinterpret_cast<const float4*>(b1 + (tid << 3));
    float4 bB = *reinterpret_cast<const float4*>(b1 + (tid << 3) + 4);
    float bv[8] = {bA.x, bA.y, bA.z, bA.w, bB.x, bB.y, bB.z, bB.w};
    #pragma unroll
    for (int jj = 0; jj < 8; ++jj)
      #pragma unroll
      for (int r = 0; r < 8; ++r) acc[jj][r] = bv[jj];
  }
  for (int k4 = 0; k4 < D_ / 4; ++k4) {
    float4 qv[8];
    #pragma unroll
    for (int r = 0; r < 8; ++r)
      qv[r] = *reinterpret_cast<const float4*>(&qs[r][k4 << 2]);
    #pragma unroll
    for (int kk = 0; kk < 4; ++kk) {
      const int k = (k4 << 2) + kk;
      float4 wA = *reinterpret_cast<const float4*>(W1 + (size_t)k * H_ + (tid << 3));
      float4 wB = *reinterpret_cast<const float4*>(W1 + (size_t)k * H_ + (tid << 3) + 4);
      float wv[8] = {wA.x, wA.y, wA.z, wA.w, wB.x, wB.y, wB.z, wB.w};
      #pragma unroll
      for (int r = 0; r < 8; ++r) {
        float qk = (kk == 0) ? qv[r].x : (kk == 1) ? qv[r].y : (kk == 2) ? qv[r].z : qv[r].w;
        #pragma unroll
        for (int jj = 0; jj < 8; ++jj) acc[jj][r] = fmaf(qk, wv[jj], acc[jj][r]);
      }
    }
  }
  #pragma unroll
  for (int jj = 0; jj < 8; ++jj)
    #pragma unroll
    for (int r = 0; r < 8; ++r) {
      float v = acc[jj][r];
      mid[r][(tid << 3) + jj] = 0.5f * v * (1.0f + erff(v * 0.70710678118654752f));
    }
  __syncthreads();
  float acc2[8][2];
  {
    float b20 = b2[tid << 1], b21 = b2[(tid << 1) + 1];
    #pragma unroll
    for (int r = 0; r < 8; ++r) { acc2[r][0] = b20; acc2[r][1] = b21; }
  }
  for (int j4 = 0; j4 < H_ / 4; ++j4) {
    float4 mv[8];
    #pragma unroll
    for (int r = 0; r < 8; ++r)
      mv[r] = *reinterpret_cast<const float4*>(&mid[r][j4 << 2]);
    #pragma unroll
    for (int kk = 0; kk < 4; ++kk) {
      const int j = (j4 << 2) + kk;
      float2 wv = *reinterpret_cast<const float2*>(W2 + (size_t)j * D_ + (tid << 1));
      #pragma unroll
      for (int r = 0; r < 8; ++r) {
        float m = (kk == 0) ? mv[r].x : (kk == 1) ? mv[r].y : (kk == 2) ? mv[r].z : mv[r].w;
        acc2[r][0] = fmaf(m, wv.x, acc2[r][0]);
        acc2[r][1] = fmaf(m, wv.y, acc2[r][1]);
      }
    }
  }
  __syncthreads();
  float* ys = &mid[0][0];
  #pragma unroll
  for (int r = 0; r < 8; ++r) {
    ys[r * D_ + (tid << 1)]     = qs[r][(tid << 1)]     + acc2[r][0];
    ys[r * D_ + (tid << 1) + 1] = qs[r][(tid << 1) + 1] + acc2[r][1];
  }
  __syncthreads();
  float g3a = g3[tid],  g3b = g3[tid + 256];
  float be3a = be3[tid], be3b = be3[tid + 256];
  float* rl = &qs[0][0];
  for (int r = 0; r < 8; ++r) {
    float v0 = ys[r * D_ + tid], v1 = ys[r * D_ + tid + 256];
    float s = v0 + v1, sq = v0 * v0 + v1 * v1;
    #pragma unroll
    for (int o = 32; o > 0; o >>= 1) { s += __shfl_down(s, o); sq += __shfl_down(sq, o); }
    int lane = tid & 63, wid = tid >> 6;
    if (lane == 0) { rl[wid] = s; rl[4 + wid] = sq; }
    __syncthreads();
    s = rl[0] + rl[1] + rl[2] + rl[3];
    sq = rl[4] + rl[5] + rl[6] + rl[7];
    __syncthreads();
    float mean = s * (1.0f / 512.0f);
    float var = sq * (1.0f / 512.0f) - mean * mean;
    float rstd = rsqrtf(var + 1e-5f);
    int t = row_base + row0 + r;
    int b = t / SQ, tt = t - b * SQ;
    int si = tt >> 3, l = tt & 7;
    size_t ob = (((size_t)(b * S_ + si) * D_) << 3) + l;
    out[ob + ((size_t)tid << 3)]         = (v0 - mean) * rstd * g3a + be3a;
    out[ob + ((size_t)(tid + 256) << 3)] = (v1 - mean) * rstd * g3b + be3b;
  }
}

extern "C" void kernel_launch(void* const* d_in, const int* in_sizes, int n_in,
                              void* d_out, int out_size, void* d_ws, size_t ws_size,
                              hipStream_t stream) {
  const float* lags   = (const float*)d_in[0];
  const float* gamma1 = (const float*)d_in[1];
  const float* beta1  = (const float*)d_in[2];
  const float* W1     = (const float*)d_in[3];
  const float* b1     = (const float*)d_in[4];
  const float* W2     = (const float*)d_in[5];
  const float* b2     = (const float*)d_in[6];
  const float* g3     = (const float*)d_in[7];
  const float* be3    = (const float*)d_in[8];
  float* out = (float*)d_out;

  float* ws = (float*)d_ws;
  const size_t NX  = (size_t)B_ * SQ * D_;   // 6,291,456
  const size_t NXB = (size_t)SQ * D_;        //   786,432
  const size_t NS  = (size_t)SQ * SQ;        // 2,359,296

  const size_t need_full = (3 * NX + 8 * NS) * sizeof(float);  // ~151 MB (proven available)

  if (ws_size >= need_full) {
    // ---- fast path layout (~130 MB) ----
    float* x        = ws;                                   // NX f32
    float* attn     = x + NX;                               // NX f32 (later: y)
    ushort_t* q_bf  = (ushort_t*)(attn + NX);               // NX us
    ushort_t* w1t   = q_bf + NX;                            // H*D us
    ushort_t* w2t   = w1t + (size_t)H_ * D_;                // H*D us
    ushort_t* region = w2t + (size_t)H_ * D_;               // 8*NS + 2*NX us
    ushort_t* sc_bf = region;                               // scores / P, bf16, in-place
    ushort_t* x_bf  = region + 8 * NS;
    ushort_t* xT_bf = x_bf + NX;
    ushort_t* mid_bf = region;                              // aliases dead sc/x_bf/xT_bf

    k_build_x_f<<<dim3(B_ * S_), 256, 0, stream>>>(lags, x, x_bf, xT_bf);
    k_wt<<<dim3(H_ / 64, D_ / 64), 256, 0, stream>>>(W1, w1t, D_, H_);
    k_wt<<<dim3(D_ / 64, H_ / 64), 256, 0, stream>>>(W2, w2t, H_, D_);
    // scores = scale * X X^T -> bf16   (grid 12x6x8, nwg=72 %8==0)
    k_gemm2<2><<<dim3(SQ / 128, SQ / 256, B_), 512, 0, stream>>>(
        x_bf, x_bf, nullptr, sc_bf, SQ, D_, SQ, NXB, NXB, NS, SCALE_QK);
    k_softmax_bf<<<dim3(SQ, 1, B_), 256, 0, stream>>>(sc_bf);
    // attn = P @ X -> f32   (grid 4x6x8, nwg=24 %8==0)
    k_gemm2<3><<<dim3(D_ / 128, SQ / 256, B_), 512, 0, stream>>>(
        sc_bf, xT_bf, nullptr, attn, SQ, SQ, D_, NS, NXB, NXB, 1.0f);
    k_ln1b<<<dim3(NROW), 256, 0, stream>>>(x, attn, gamma1, beta1, q_bf);
    // mid = gelu(q @ W1 + b1) -> bf16   (grid 16x48, nwg=768 %8==0)
    k_gemm2<0><<<dim3(H_ / 128, NROW / 256, 1), 512, 0, stream>>>(
        q_bf, w1t, b1, mid_bf, NROW, D_, H_, 0, 0, 0, 1.0f);
    // y = mid @ W2 + b2 -> f32 (attn buffer)   (grid 4x48, nwg=192 %8==0)
    k_gemm2<1><<<dim3(D_ / 128, NROW / 256, 1), 512, 0, stream>>>(
        mid_bf, w2t, b2, attn, NROW, H_, D_, 0, 0, 0, 1.0f);
    k_ln3_f<<<dim3(B_ * S_), 256, 0, stream>>>(attn, q_bf, g3, be3, out);
  } else {
    // ---- minimal-footprint fallback (fp32, per-batch) ----
    float* xb   = ws;
    float* sc   = xb + NXB;
    float* atb  = sc + NS;
    float* qb   = atb + NXB;
    for (int b = 0; b < B_; ++b) {
      k_build_x_s<<<dim3((unsigned)(NXB / 256)), 256, 0, stream>>>(lags, xb, b);
      k_scores<<<dim3(SQ / TS, SQ / TS, 1), 256, 0, stream>>>(xb, sc, b);
      k_softmax<<<dim3(SQ, 1, 1), 256, 0, stream>>>(sc);
      k_attn<<<dim3(D_ / TS, SQ / TS, 1), 256, 0, stream>>>(xb, sc, atb);
      k_ln1<<<dim3(SQ), 256, 0, stream>>>(xb, atb, gamma1, beta1, qb);
      k_ffn<<<dim3(SQ / 8), 256, 0, stream>>>(qb, W1, b1, W2, b2, g3, be3, out, b * SQ);
    }
  }
}

// Round 8
// 294.607 us; speedup vs baseline: 1.0310x; 1.0261x over previous
//
#include <hip/hip_runtime.h>
#include <hip/hip_bf16.h>
#include <math.h>

#define B_ 8
#define S_ 192
#define D_ 512
#define L_ 8
#define SQ 1536   // S_*L_
#define H_ 2048
#define NROW (B_*SQ)   // 12288
#define SCALE_QK 0.04419417382415922f   // 1/sqrt(512)
#define SCALE_QK2 0.06377551974755906f  // SCALE_QK * log2(e)

typedef unsigned short ushort_t;
typedef unsigned int uint_t;
typedef __attribute__((ext_vector_type(8))) short bf16x8;
typedef __attribute__((ext_vector_type(4))) float f32x4;

__device__ __forceinline__ float bfu2f(ushort_t u) { return __uint_as_float((unsigned)u << 16); }
__device__ __forceinline__ ushort_t f2bfu(float f) {
  __hip_bfloat16 h = __float2bfloat16(f);
  return *reinterpret_cast<ushort_t*>(&h);
}

// tanh-form GELU: 0.5x(1+tanh(0.79788456(x+0.044715x^3))), max |err| ~3e-4.
__device__ __forceinline__ float gelu_tanh(float x) {
  float x2 = x * x;
  float u2 = x * fmaf(0.0713548162f, x2, 1.5957691216f);
  float e = __expf(u2);                       // e^(2u)
  float r = fmaf(-2.0f, __builtin_amdgcn_rcpf(e + 1.0f), 1.0f);  // tanh(u)
  float hx = 0.5f * x;
  return fmaf(hx, r, hx);
}

// async global->LDS, 16B per lane; LDS dest = wave-uniform base + lane*16
__device__ __forceinline__ void gl_lds16(const ushort_t* g, ushort_t* l) {
  __builtin_amdgcn_global_load_lds(
      (const __attribute__((address_space(1))) unsigned int*)g,
      (__attribute__((address_space(3))) unsigned int*)l, 16, 0, 0);
}

// counted vmcnt wait: leaves N newest VMEM ops in flight (T4).
#define VMWAIT(N) asm volatile("s_waitcnt vmcnt(" #N ")" ::: "memory")

// ---- zero a float buffer (graph-capture-safe replacement for hipMemsetAsync) ----
__global__ __launch_bounds__(256) void k_zero(float* __restrict__ p) {
  p[(size_t)blockIdx.x * 256 + threadIdx.x] = 0.f;
}

// ---- fast build x: one block per (b,si); coalesced read of 4096 floats, LDS transpose.
// Emits x (f32), x_bf (bf16) and xT_bf ([B][D][SQ]) directly.
__global__ __launch_bounds__(256) void k_build_x_f(const float* __restrict__ lags,
                                                   float* __restrict__ x,
                                                   ushort_t* __restrict__ x_bf,
                                                   ushort_t* __restrict__ xT) {
  __shared__ float tile[512][9];
  const int tid = threadIdx.x;
  const float* in = lags + (size_t)blockIdx.x * 4096;
  #pragma unroll
  for (int it = 0; it < 4; ++it) {
    int f = (tid + it * 256) * 4;
    float4 v = *reinterpret_cast<const float4*>(in + f);
    int k = f >> 3, l0 = f & 7;
    tile[k][l0] = v.x; tile[k][l0 + 1] = v.y; tile[k][l0 + 2] = v.z; tile[k][l0 + 3] = v.w;
  }
  __syncthreads();
  const int l = tid >> 5, kbase = tid & 31;
  const size_t r = (size_t)blockIdx.x * 8 + l;
  #pragma unroll
  for (int j = 0; j < 16; ++j) {
    int k = kbase + 32 * j;
    float v = tile[k][l];
    x[r * D_ + k] = v;
    x_bf[r * D_ + k] = f2bfu(v);
  }
  const int b = blockIdx.x / S_, si = blockIdx.x - b * S_;
  #pragma unroll
  for (int dd = 0; dd < 2; ++dd) {
    int d = tid + dd * 256;
    uint_t pk[4];
    #pragma unroll
    for (int j = 0; j < 4; ++j) {
      uint_t lo = f2bfu(tile[d][2 * j]);
      uint_t hi = f2bfu(tile[d][2 * j + 1]);
      pk[j] = (hi << 16) | lo;
    }
    uint_t* dst = (uint_t*)(xT + ((size_t)b * D_ + d) * SQ + si * 8);
    *reinterpret_cast<uint4*>(dst) = make_uint4(pk[0], pk[1], pk[2], pk[3]);
  }
}

// ---- cast + transpose weights: W[K][N] fp32 -> Wt[N][K] bf16 ----
__global__ __launch_bounds__(256) void k_wt(const float* __restrict__ W,
                                            ushort_t* __restrict__ Wt,
                                            int K, int N) {
  __shared__ ushort_t tile[64][65];
  int n0 = blockIdx.x * 64, k0 = blockIdx.y * 64;
  for (int i = threadIdx.x; i < 4096; i += 256) {
    int kk = i >> 6, nn = i & 63;
    tile[nn][kk] = f2bfu(W[(size_t)(k0 + kk) * N + n0 + nn]);
  }
  __syncthreads();
  for (int i = threadIdx.x; i < 4096; i += 256) {
    int nn = i >> 6, kk = i & 63;
    Wt[(size_t)(n0 + nn) * K + k0 + kk] = tile[nn][kk];
  }
}

// ---- bf16 MFMA GEMM (r3 core: 128x128 tile, 4 waves, BK=64, 2-buffer
// counted-vmcnt pipeline, zero-conflict swizzled LDS):  C = A[M,K] @ Bt[N,K]^T
// MODE 0: +bias, gelu -> bf16      | 1: +bias -> f32
// MODE 4: exp2(v*scale) -> bf16, accumulate per-row sums into rsums (atomicAdd)
// MODE 5: v * rcp(rsums[row]) -> f32   (softmax normalization folded in)
// bias: MODE<=1 only. rsums: MODE 4 written / MODE 5 read; batch stride SQ.
template<int MODE>
__global__ __launch_bounds__(256) void k_gemm(const ushort_t* __restrict__ A,
                                              const ushort_t* __restrict__ Bt,
                                              const float* __restrict__ bias,
                                              float* __restrict__ rsums,
                                              void* __restrict__ Cout,
                                              int M, int K, int N,
                                              size_t sAz, size_t sBz, size_t sCz,
                                              float scale) {
  A  += (size_t)blockIdx.z * sAz;
  Bt += (size_t)blockIdx.z * sBz;
  __shared__ ushort_t As0[128 * 64];   // 16 KB each, 64 KB total -> 2 blocks/CU
  __shared__ ushort_t As1[128 * 64];
  __shared__ ushort_t Bs0[128 * 64];
  __shared__ ushort_t Bs1[128 * 64];
  const int tid = threadIdx.x;
  const int m0 = blockIdx.y * 128, n0 = blockIdx.x * 128;
  const int w = tid >> 6, lane = tid & 63;
  const int wr = w >> 1, wc = w & 1;
  const int l15 = lane & 15, quad = lane >> 4;
  const int lrow8 = lane >> 3;                    // 0..7: staging row within 8-row group
  const int cg = ((lane & 7) ^ lrow8) * 8;        // swizzled global source chunk (ushorts)
  const int xsw = l15 & 7;                        // fragment-read xor
  const int lbase = (w * 32) * 64;                // wave-uniform LDS base offset
  const size_t sK8 = (size_t)8 * K;

  f32x4 acc[4][4];
  if (MODE <= 1) {
    #pragma unroll
    for (int nj = 0; nj < 4; ++nj) {
      float bv = bias[n0 + wc * 64 + nj * 16 + l15];
      #pragma unroll
      for (int mi = 0; mi < 4; ++mi) acc[mi][nj] = (f32x4){bv, bv, bv, bv};
    }
  } else {
    #pragma unroll
    for (int nj = 0; nj < 4; ++nj)
      #pragma unroll
      for (int mi = 0; mi < 4; ++mi) acc[mi][nj] = (f32x4){0.f, 0.f, 0.f, 0.f};
  }

  // per-thread staging source pointers; advance by 64 ushorts per staged tile
  const ushort_t* gA = A  + (size_t)(m0 + w * 32 + lrow8) * K + cg;
  const ushort_t* gB = Bt + (size_t)(n0 + w * 32 + lrow8) * K + cg;

#define STAGE(AS, BS) do {                                                  \
    ushort_t* la_ = &AS[lbase]; ushort_t* lb_ = &BS[lbase];                 \
    _Pragma("unroll")                                                       \
    for (int j_ = 0; j_ < 4; ++j_) {                                        \
      gl_lds16(gA + (size_t)j_ * sK8, la_ + j_ * 8 * 64);                   \
      gl_lds16(gB + (size_t)j_ * sK8, lb_ + j_ * 8 * 64);                   \
    }                                                                       \
    gA += 64; gB += 64;                                                     \
  } while (0)

#define COMPUTE(AS, BS) do {                                                \
    _Pragma("unroll")                                                       \
    for (int kk_ = 0; kk_ < 2; ++kk_) {                                     \
      const int csel_ = ((kk_ * 4 + quad) ^ xsw) * 8;                       \
      bf16x8 af_[4], bf_[4];                                                \
      _Pragma("unroll")                                                     \
      for (int mi_ = 0; mi_ < 4; ++mi_)                                     \
        af_[mi_] = *reinterpret_cast<const bf16x8*>(                        \
            &AS[(wr * 64 + mi_ * 16 + l15) * 64 + csel_]);                  \
      _Pragma("unroll")                                                     \
      for (int nj_ = 0; nj_ < 4; ++nj_)                                     \
        bf_[nj_] = *reinterpret_cast<const bf16x8*>(                        \
            &BS[(wc * 64 + nj_ * 16 + l15) * 64 + csel_]);                  \
      _Pragma("unroll")                                                     \
      for (int mi_ = 0; mi_ < 4; ++mi_)                                     \
        _Pragma("unroll")                                                   \
        for (int nj_ = 0; nj_ < 4; ++nj_)                                   \
          acc[mi_][nj_] = __builtin_amdgcn_mfma_f32_16x16x32_bf16(          \
              af_[mi_], bf_[nj_], acc[mi_][nj_], 0, 0, 0);                  \
    }                                                                       \
  } while (0)

  // prologue: stage tiles 0 and 1 (16 loads/wave in flight)
  STAGE(As0, Bs0);
  STAGE(As1, Bs1);

  const int nt = K >> 6;   // even, >= 8 for all call sites
  for (int t = 0; t < nt - 2; t += 2) {
    VMWAIT(8);                        // tile t landed; tile t+1 stays in flight
    __builtin_amdgcn_s_barrier();
    COMPUTE(As0, Bs0);                // compute tile t
    __builtin_amdgcn_s_barrier();     // join: all waves done reading buf0
    STAGE(As0, Bs0);                  // prefetch tile t+2
    VMWAIT(8);                        // tile t+1 landed; tile t+2 in flight
    __builtin_amdgcn_s_barrier();
    COMPUTE(As1, Bs1);                // compute tile t+1
    __builtin_amdgcn_s_barrier();     // join: all waves done reading buf1
    STAGE(As1, Bs1);                  // prefetch tile t+3
  }
  // tail: tiles nt-2 (buf0) and nt-1 (buf1) staged, nothing more to prefetch
  VMWAIT(8);
  __builtin_amdgcn_s_barrier();
  COMPUTE(As0, Bs0);
  VMWAIT(0);
  __builtin_amdgcn_s_barrier();
  COMPUTE(As1, Bs1);

#undef STAGE
#undef COMPUTE

  ushort_t* Cb = (ushort_t*)Cout + (size_t)blockIdx.z * sCz;
  float*    Cf = (float*)Cout    + (size_t)blockIdx.z * sCz;

  if (MODE == 4) {
    // exp-scores epilogue: store bf16 exp(scale*v), row-sum -> atomicAdd.
    float* rs = rsums + (size_t)blockIdx.z * SQ;
    #pragma unroll
    for (int mi = 0; mi < 4; ++mi)
      #pragma unroll
      for (int r = 0; r < 4; ++r) {
        int gr = m0 + wr * 64 + mi * 16 + quad * 4 + r;
        float s = 0.f;
        #pragma unroll
        for (int nj = 0; nj < 4; ++nj) {
          int gc = n0 + wc * 64 + nj * 16 + l15;
          float e = exp2f(acc[mi][nj][r] * scale);   // scale includes log2(e)
          ushort_t ub = f2bfu(e);
          Cb[(size_t)gr * N + gc] = ub;
          s += bfu2f(ub);                            // sum the ROUNDED values
        }
        #pragma unroll
        for (int m_ = 1; m_ < 16; m_ <<= 1) s += __shfl_xor(s, m_);
        if (l15 == 0) atomicAdd(&rs[gr], s);
      }
  } else {
    const float* rs = rsums + (size_t)blockIdx.z * SQ;  // MODE 5 only
    #pragma unroll
    for (int mi = 0; mi < 4; ++mi)
      #pragma unroll
      for (int nj = 0; nj < 4; ++nj) {
        int gc = n0 + wc * 64 + nj * 16 + l15;
        #pragma unroll
        for (int r = 0; r < 4; ++r) {
          int gr = m0 + wr * 64 + mi * 16 + quad * 4 + r;
          float v = acc[mi][nj][r];
          if (MODE == 0) {
            Cb[(size_t)gr * N + gc] = f2bfu(gelu_tanh(v));
          } else if (MODE == 1) {
            Cf[(size_t)gr * N + gc] = v;
          } else if (MODE == 5) {
            Cf[(size_t)gr * N + gc] = v * __builtin_amdgcn_rcpf(rs[gr]);
          } else {
            Cf[(size_t)gr * N + gc] = v;
          }
        }
      }
  }
}

// ---- LN1 -> bf16 q ----
__global__ __launch_bounds__(256) void k_ln1b(const float* __restrict__ x,
                                              const float* __restrict__ attn,
                                              const float* __restrict__ g,
                                              const float* __restrict__ be,
                                              ushort_t* __restrict__ qbf) {
  size_t base = (size_t)blockIdx.x * D_;
  int tid = threadIdx.x;
  __shared__ float rl[8];
  float v0 = x[base + tid] + attn[base + tid];
  float v1 = x[base + tid + 256] + attn[base + tid + 256];
  float s = v0 + v1, sq = v0 * v0 + v1 * v1;
  #pragma unroll
  for (int o = 32; o > 0; o >>= 1) { s += __shfl_down(s, o); sq += __shfl_down(sq, o); }
  int lane = tid & 63, wid = tid >> 6;
  if (lane == 0) { rl[wid] = s; rl[4 + wid] = sq; }
  __syncthreads();
  s = rl[0] + rl[1] + rl[2] + rl[3];
  sq = rl[4] + rl[5] + rl[6] + rl[7];
  float mean = s * (1.0f / 512.0f);
  float var = sq * (1.0f / 512.0f) - mean * mean;
  float rstd = rsqrtf(var + 1e-5f);
  qbf[base + tid]       = f2bfu((v0 - mean) * rstd * g[tid] + be[tid]);
  qbf[base + tid + 256] = f2bfu((v1 - mean) * rstd * g[tid + 256] + be[tid + 256]);
}

// ---- fast LN3: one block per (b,si); LDS transpose -> fully coalesced output ----
__global__ __launch_bounds__(256) void k_ln3_f(const float* __restrict__ y,
                                               const ushort_t* __restrict__ qbf,
                                               const float* __restrict__ g3,
                                               const float* __restrict__ be3,
                                               float* __restrict__ out) {
  __shared__ float ynorm[8][512];
  const int tid = threadIdx.x;
  const int w = tid >> 6, lane = tid & 63;
  #pragma unroll
  for (int rr = 0; rr < 2; ++rr) {
    int l = 2 * w + rr;
    size_t t = (size_t)blockIdx.x * 8 + l;
    float v[8];
    float s = 0.f, sq = 0.f;
    #pragma unroll
    for (int j = 0; j < 8; ++j) {
      int k = lane + 64 * j;
      v[j] = y[t * D_ + k] + bfu2f(qbf[t * D_ + k]);
      s += v[j]; sq += v[j] * v[j];
    }
    #pragma unroll
    for (int o = 32; o > 0; o >>= 1) { s += __shfl_down(s, o); sq += __shfl_down(sq, o); }
    s = __shfl(s, 0); sq = __shfl(sq, 0);
    float mean = s * (1.0f / 512.0f);
    float var = sq * (1.0f / 512.0f) - mean * mean;
    float rstd = rsqrtf(var + 1e-5f);
    #pragma unroll
    for (int j = 0; j < 8; ++j) {
      int k = lane + 64 * j;
      ynorm[l][k] = (v[j] - mean) * rstd * g3[k] + be3[k];
    }
  }
  __syncthreads();
  float* ob = out + (size_t)blockIdx.x * 4096;
  #pragma unroll
  for (int kk = 0; kk < 2; ++kk) {
    int k = tid * 2 + kk;
    float4 lo = make_float4(ynorm[0][k], ynorm[1][k], ynorm[2][k], ynorm[3][k]);
    float4 hi = make_float4(ynorm[4][k], ynorm[5][k], ynorm[6][k], ynorm[7][k]);
    *reinterpret_cast<float4*>(ob + (size_t)k * 8)     = lo;
    *reinterpret_cast<float4*>(ob + (size_t)k * 8 + 4) = hi;
  }
}

// ================= slow-path fp32 kernels (fallback only) =================
#define TS 64
#define KT 16
__global__ __launch_bounds__(256) void k_build_x_s(const float* __restrict__ lags,
                                                   float* __restrict__ x, int b_base) {
  int idx = blockIdx.x * 256 + threadIdx.x;
  int k = idx & (D_ - 1);
  int r = idx >> 9;
  int b = b_base + r / SQ;
  int t = r - (r / SQ) * SQ;
  int si = t >> 3, l = t & 7;
  size_t src = (((size_t)(b * S_ + si) * D_ + k) << 3) + l;
  x[idx] = lags[src];
}

__global__ __launch_bounds__(256) void k_scores(const float* __restrict__ x,
                                                float* __restrict__ sc, int b_base) {
  const float* A = x;
  float* C = sc;
  __shared__ float As[TS][KT + 1];
  __shared__ float Bs[TS][KT + 1];
  int tx = threadIdx.x & 15, ty = threadIdx.x >> 4;
  int j0 = blockIdx.x * TS, i0 = blockIdx.y * TS;
  float acc[4][4] = {};
  int lk = threadIdx.x & 15, lr = threadIdx.x >> 4;
  for (int k0 = 0; k0 < D_; k0 += KT) {
    #pragma unroll
    for (int it = 0; it < 4; ++it) {
      As[lr + 16 * it][lk] = A[(size_t)(i0 + lr + 16 * it) * D_ + k0 + lk];
      Bs[lr + 16 * it][lk] = A[(size_t)(j0 + lr + 16 * it) * D_ + k0 + lk];
    }
    __syncthreads();
    #pragma unroll
    for (int kk = 0; kk < KT; ++kk) {
      float a[4], bb[4];
      #pragma unroll
      for (int r = 0; r < 4; ++r) a[r] = As[ty * 4 + r][kk];
      #pragma unroll
      for (int c = 0; c < 4; ++c) bb[c] = Bs[tx * 4 + c][kk];
      #pragma unroll
      for (int r = 0; r < 4; ++r)
        #pragma unroll
        for (int c = 0; c < 4; ++c) acc[r][c] = fmaf(a[r], bb[c], acc[r][c]);
    }
    __syncthreads();
  }
  #pragma unroll
  for (int r = 0; r < 4; ++r) {
    float4 v = make_float4(acc[r][0]*SCALE_QK, acc[r][1]*SCALE_QK,
                           acc[r][2]*SCALE_QK, acc[r][3]*SCALE_QK);
    *reinterpret_cast<float4*>(&C[(size_t)(i0 + ty*4 + r) * SQ + j0 + tx*4]) = v;
  }
}

__global__ __launch_bounds__(256) void k_softmax(float* __restrict__ sc) {
  float* row = sc + (size_t)blockIdx.x * SQ;
  int tid = threadIdx.x;
  __shared__ float red[8];
  float m = -1e30f;
  for (int j = tid; j < SQ; j += 256) m = fmaxf(m, row[j]);
  #pragma unroll
  for (int o = 32; o > 0; o >>= 1) m = fmaxf(m, __shfl_down(m, o));
  if ((tid & 63) == 0) red[tid >> 6] = m;
  __syncthreads();
  m = fmaxf(fmaxf(red[0], red[1]), fmaxf(red[2], red[3]));
  __syncthreads();
  float ssum = 0.f;
  for (int j = tid; j < SQ; j += 256) { float e = expf(row[j] - m); row[j] = e; ssum += e; }
  #pragma unroll
  for (int o = 32; o > 0; o >>= 1) ssum += __shfl_down(ssum, o);
  if ((tid & 63) == 0) red[4 + (tid >> 6)] = ssum;
  __syncthreads();
  float inv = 1.0f / (red[4] + red[5] + red[6] + red[7]);
  for (int j = tid; j < SQ; j += 256) row[j] *= inv;
}

__global__ __launch_bounds__(256) void k_attn(const float* __restrict__ x,
                                              const float* __restrict__ sc,
                                              float* __restrict__ attn) {
  const float* X = x;
  const float* P = sc;
  float* O = attn;
  __shared__ float Ps[TS][KT + 1];
  __shared__ float Xs[KT][TS];
  int tx = threadIdx.x & 15, ty = threadIdx.x >> 4;
  int j0 = blockIdx.x * TS, i0 = blockIdx.y * TS;
  float acc[4][4] = {};
  int lk = threadIdx.x & 15, lr = threadIdx.x >> 4;
  int lc = threadIdx.x & 63, lrow = threadIdx.x >> 6;
  for (int k0 = 0; k0 < SQ; k0 += KT) {
    #pragma unroll
    for (int it = 0; it < 4; ++it)
      Ps[lr + 16 * it][lk] = P[(size_t)(i0 + lr + 16 * it) * SQ + k0 + lk];
    #pragma unroll
    for (int it = 0; it < 4; ++it)
      Xs[lrow + 4 * it][lc] = X[(size_t)(k0 + lrow + 4 * it) * D_ + j0 + lc];
    __syncthreads();
    #pragma unroll
    for (int kk = 0; kk < KT; ++kk) {
      float a[4], bb[4];
      #pragma unroll
      for (int r = 0; r < 4; ++r) a[r] = Ps[ty * 4 + r][kk];
      #pragma unroll
      for (int c = 0; c < 4; ++c) bb[c] = Xs[kk][tx * 4 + c];
      #pragma unroll
      for (int r = 0; r < 4; ++r)
        #pragma unroll
        for (int c = 0; c < 4; ++c) acc[r][c] = fmaf(a[r], bb[c], acc[r][c]);
    }
    __syncthreads();
  }
  #pragma unroll
  for (int r = 0; r < 4; ++r) {
    float4 v = make_float4(acc[r][0], acc[r][1], acc[r][2], acc[r][3]);
    *reinterpret_cast<float4*>(&O[(size_t)(i0 + ty*4 + r) * D_ + j0 + tx*4]) = v;
  }
}

__global__ __launch_bounds__(256) void k_ln1(const float* __restrict__ x,
                                             const float* __restrict__ attn,
                                             const float* __restrict__ g,
                                             const float* __restrict__ be,
                                             float* __restrict__ qout) {
  size_t base = (size_t)blockIdx.x * D_;
  int tid = threadIdx.x;
  __shared__ float rl[8];
  float v0 = x[base + tid] + attn[base + tid];
  float v1 = x[base + tid + 256] + attn[base + tid + 256];
  float s = v0 + v1, sq = v0 * v0 + v1 * v1;
  #pragma unroll
  for (int o = 32; o > 0; o >>= 1) { s += __shfl_down(s, o); sq += __shfl_down(sq, o); }
  int lane = tid & 63, wid = tid >> 6;
  if (lane == 0) { rl[wid] = s; rl[4 + wid] = sq; }
  __syncthreads();
  s = rl[0] + rl[1] + rl[2] + rl[3];
  sq = rl[4] + rl[5] + rl[6] + rl[7];
  float mean = s * (1.0f / 512.0f);
  float var = sq * (1.0f / 512.0f) - mean * mean;
  float rstd = rsqrtf(var + 1e-5f);
  qout[base + tid]       = (v0 - mean) * rstd * g[tid] + be[tid];
  qout[base + tid + 256] = (v1 - mean) * rstd * g[tid + 256] + be[tid + 256];
}

__global__ __launch_bounds__(256, 2) void k_ffn(
    const float* __restrict__ q,
    const float* __restrict__ W1, const float* __restrict__ b1,
    const float* __restrict__ W2, const float* __restrict__ b2,
    const float* __restrict__ g3, const float* __restrict__ be3,
    float* __restrict__ out, int row_base)
{
  __shared__ float qs[8][D_];
  __shared__ float mid[8][H_];
  const int tid = threadIdx.x;
  const int row0 = blockIdx.x * 8;
  for (int idx = tid; idx < 8 * D_; idx += 256)
    qs[idx >> 9][idx & (D_ - 1)] = q[(size_t)row0 * D_ + idx];
  __syncthreads();
  float acc[8][8];
  {
    float4 bA = *reinterpret_cast<const float4*>(b1 + (tid << 3));
    float4 bB = *reinterpret_cast<const float4*>(b1 + (tid << 3) + 4);
    float bv[8] = {bA.x, bA.y, bA.z, bA.w, bB.x, bB.y, bB.z, bB.w};
    #pragma unroll
    for (int jj = 0; jj < 8; ++jj)
      #pragma unroll
      for (int r = 0; r < 8; ++r) acc[jj][r] = bv[jj];
  }
  for (int k4 = 0; k4 < D_ / 4; ++k4) {
    float4 qv[8];
    #pragma unroll
    for (int r = 0; r < 8; ++r)
      qv[r] = *reinterpret_cast<const float4*>(&qs[r][k4 << 2]);
    #pragma unroll
    for (int kk = 0; kk < 4; ++kk) {
      const int k = (k4 << 2) + kk;
      float4 wA = *reinterpret_cast<const float4*>(W1 + (size_t)k * H_ + (tid << 3));
      float4 wB = *reinterpret_cast<const float4*>(W1 + (size_t)k * H_ + (tid << 3) + 4);
      float wv[8] = {wA.x, wA.y, wA.z, wA.w, wB.x, wB.y, wB.z, wB.w};
      #pragma unroll
      for (int r = 0; r < 8; ++r) {
        float qk = (kk == 0) ? qv[r].x : (kk == 1) ? qv[r].y : (kk == 2) ? qv[r].z : qv[r].w;
        #pragma unroll
        for (int jj = 0; jj < 8; ++jj) acc[jj][r] = fmaf(qk, wv[jj], acc[jj][r]);
      }
    }
  }
  #pragma unroll
  for (int jj = 0; jj < 8; ++jj)
    #pragma unroll
    for (int r = 0; r < 8; ++r) {
      float v = acc[jj][r];
      mid[r][(tid << 3) + jj] = 0.5f * v * (1.0f + erff(v * 0.70710678118654752f));
    }
  __syncthreads();
  float acc2[8][2];
  {
    float b20 = b2[tid << 1], b21 = b2[(tid << 1) + 1];
    #pragma unroll
    for (int r = 0; r < 8; ++r) { acc2[r][0] = b20; acc2[r][1] = b21; }
  }
  for (int j4 = 0; j4 < H_ / 4; ++j4) {
    float4 mv[8];
    #pragma unroll
    for (int r = 0; r < 8; ++r)
      mv[r] = *reinterpret_cast<const float4*>(&mid[r][j4 << 2]);
    #pragma unroll
    for (int kk = 0; kk < 4; ++kk) {
      const int j = (j4 << 2) + kk;
      float2 wv = *reinterpret_cast<const float2*>(W2 + (size_t)j * D_ + (tid << 1));
      #pragma unroll
      for (int r = 0; r < 8; ++r) {
        float m = (kk == 0) ? mv[r].x : (kk == 1) ? mv[r].y : (kk == 2) ? mv[r].z : mv[r].w;
        acc2[r][0] = fmaf(m, wv.x, acc2[r][0]);
        acc2[r][1] = fmaf(m, wv.y, acc2[r][1]);
      }
    }
  }
  __syncthreads();
  float* ys = &mid[0][0];
  #pragma unroll
  for (int r = 0; r < 8; ++r) {
    ys[r * D_ + (tid << 1)]     = qs[r][(tid << 1)]     + acc2[r][0];
    ys[r * D_ + (tid << 1) + 1] = qs[r][(tid << 1) + 1] + acc2[r][1];
  }
  __syncthreads();
  float g3a = g3[tid],  g3b = g3[tid + 256];
  float be3a = be3[tid], be3b = be3[tid + 256];
  float* rl = &qs[0][0];
  for (int r = 0; r < 8; ++r) {
    float v0 = ys[r * D_ + tid], v1 = ys[r * D_ + tid + 256];
    float s = v0 + v1, sq = v0 * v0 + v1 * v1;
    #pragma unroll
    for (int o = 32; o > 0; o >>= 1) { s += __shfl_down(s, o); sq += __shfl_down(sq, o); }
    int lane = tid & 63, wid = tid >> 6;
    if (lane == 0) { rl[wid] = s; rl[4 + wid] = sq; }
    __syncthreads();
    s = rl[0] + rl[1] + rl[2] + rl[3];
    sq = rl[4] + rl[5] + rl[6] + rl[7];
    __syncthreads();
    float mean = s * (1.0f / 512.0f);
    float var = sq * (1.0f / 512.0f) - mean * mean;
    float rstd = rsqrtf(var + 1e-5f);
    int t = row_base + row0 + r;
    int b = t / SQ, tt = t - b * SQ;
    int si = tt >> 3, l = tt & 7;
    size_t ob = (((size_t)(b * S_ + si) * D_) << 3) + l;
    out[ob + ((size_t)tid << 3)]         = (v0 - mean) * rstd * g3a + be3a;
    out[ob + ((size_t)(tid + 256) << 3)] = (v1 - mean) * rstd * g3b + be3b;
  }
}

extern "C" void kernel_launch(void* const* d_in, const int* in_sizes, int n_in,
                              void* d_out, int out_size, void* d_ws, size_t ws_size,
                              hipStream_t stream) {
  const float* lags   = (const float*)d_in[0];
  const float* gamma1 = (const float*)d_in[1];
  const float* beta1  = (const float*)d_in[2];
  const float* W1     = (const float*)d_in[3];
  const float* b1     = (const float*)d_in[4];
  const float* W2     = (const float*)d_in[5];
  const float* b2     = (const float*)d_in[6];
  const float* g3     = (const float*)d_in[7];
  const float* be3    = (const float*)d_in[8];
  float* out = (float*)d_out;

  float* ws = (float*)d_ws;
  const size_t NX  = (size_t)B_ * SQ * D_;   // 6,291,456
  const size_t NXB = (size_t)SQ * D_;        //   786,432
  const size_t NS  = (size_t)SQ * SQ;        // 2,359,296

  const size_t need_full = (3 * NX + 8 * NS) * sizeof(float);  // ~151 MB (proven available)

  if (ws_size >= need_full) {
    // ---- fast path layout (~130 MB) ----
    float* x        = ws;                                   // NX f32
    float* attn     = x + NX;                               // NX f32 (later: y)
    ushort_t* q_bf  = (ushort_t*)(attn + NX);               // NX us
    ushort_t* w1t   = q_bf + NX;                            // H*D us
    ushort_t* w2t   = w1t + (size_t)H_ * D_;                // H*D us
    float* rowsum   = (float*)(w2t + (size_t)H_ * D_);      // B*SQ f32 (48 KB)
    ushort_t* region = (ushort_t*)(rowsum + (size_t)B_ * SQ); // 8*NS + 2*NX us
    ushort_t* sc_bf = region;                               // exp-scores, bf16
    ushort_t* x_bf  = region + 8 * NS;
    ushort_t* xT_bf = x_bf + NX;
    ushort_t* mid_bf = region;                              // aliases dead sc/x_bf/xT_bf

    k_build_x_f<<<dim3(B_ * S_), 256, 0, stream>>>(lags, x, x_bf, xT_bf);
    k_wt<<<dim3(H_ / 64, D_ / 64), 256, 0, stream>>>(W1, w1t, D_, H_);
    k_wt<<<dim3(D_ / 64, H_ / 64), 256, 0, stream>>>(W2, w2t, H_, D_);
    k_zero<<<dim3(B_ * SQ / 256), 256, 0, stream>>>(rowsum);
    // P = exp(scale * X X^T) -> bf16, rowsum accumulated (no max-sub needed:
    // scores bounded by max ||x||^2/sqrt(d) ~ 31 -> exp <= 3e13, f32-safe)
    k_gemm<4><<<dim3(SQ / 128, SQ / 128, B_), 256, 0, stream>>>(
        x_bf, x_bf, nullptr, rowsum, sc_bf, SQ, D_, SQ, NXB, NXB, NS, SCALE_QK2);
    // attn = (P @ X) / rowsum -> f32  (softmax normalization folded in)
    k_gemm<5><<<dim3(D_ / 128, SQ / 128, B_), 256, 0, stream>>>(
        sc_bf, xT_bf, nullptr, rowsum, attn, SQ, SQ, D_, NS, NXB, NXB, 1.0f);
    k_ln1b<<<dim3(NROW), 256, 0, stream>>>(x, attn, gamma1, beta1, q_bf);
    // mid = gelu(q @ W1 + b1) -> bf16
    k_gemm<0><<<dim3(H_ / 128, NROW / 128, 1), 256, 0, stream>>>(
        q_bf, w1t, b1, nullptr, mid_bf, NROW, D_, H_, 0, 0, 0, 1.0f);
    // y = mid @ W2 + b2 -> f32 (attn buffer)
    k_gemm<1><<<dim3(D_ / 128, NROW / 128, 1), 256, 0, stream>>>(
        mid_bf, w2t, b2, nullptr, attn, NROW, H_, D_, 0, 0, 0, 1.0f);
    k_ln3_f<<<dim3(B_ * S_), 256, 0, stream>>>(attn, q_bf, g3, be3, out);
  } else {
    // ---- minimal-footprint fallback (fp32, per-batch) ----
    float* xb   = ws;
    float* sc   = xb + NXB;
    float* atb  = sc + NS;
    float* qb   = atb + NXB;
    for (int b = 0; b < B_; ++b) {
      k_build_x_s<<<dim3((unsigned)(NXB / 256)), 256, 0, stream>>>(lags, xb, b);
      k_scores<<<dim3(SQ / TS, SQ / TS, 1), 256, 0, stream>>>(xb, sc, b);
      k_softmax<<<dim3(SQ, 1, 1), 256, 0, stream>>>(sc);
      k_attn<<<dim3(D_ / TS, SQ / TS, 1), 256, 0, stream>>>(xb, sc, atb);
      k_ln1<<<dim3(SQ), 256, 0, stream>>>(xb, atb, gamma1, beta1, qb);
      k_ffn<<<dim3(SQ / 8), 256, 0, stream>>>(qb, W1, b1, W2, b2, g3, be3, out, b * SQ);
    }
  }
}